// Round 6
// baseline (3373.922 us; speedup 1.0000x reference)
//
#include <hip/hip_runtime.h>
#include <math.h>

#define B 64
#define S 512
#define H 512
#define G4 2048  // 4*H gate columns

typedef __attribute__((ext_vector_type(8))) short bf16x8;
typedef __attribute__((ext_vector_type(4))) float f32x4;

__device__ __forceinline__ float sigmoidf_(float x) {
    return 1.0f / (1.0f + __expf(-x));
}
__device__ __forceinline__ float tanhf_(float x) {
    return 2.0f / (1.0f + __expf(-2.0f * x)) - 1.0f;
}

// bf16 <-> f32 via raw bits (RNE)
__device__ __forceinline__ ushort f2bf(float f) {
    union { float f; unsigned int u; } v; v.f = f;
    unsigned int r = v.u + 0x7FFFu + ((v.u >> 16) & 1u);
    return (ushort)(r >> 16);
}
__device__ __forceinline__ float bf2f(ushort s) {
    union { unsigned int u; float f; } v; v.u = ((unsigned int)s) << 16;
    return v.f;
}
// split f32 into bf16 hi + bf16 lo, x ~= hi + lo to ~2^-18 rel
__device__ __forceinline__ void split_bf(float x, ushort& hi, ushort& lo) {
    const ushort h = f2bf(x);
    hi = h;
    lo = f2bf(x - bf2f(h));
}

// ---------------------------------------------------------------------------
// Pre-pass: split a f32 [2048][512] weight into bf16 hi/lo planes, once.
// ---------------------------------------------------------------------------
__global__ __launch_bounds__(256)
void w_split(const float* __restrict__ W,
             ushort* __restrict__ Whi,
             ushort* __restrict__ Wlo)
{
    const int i = blockIdx.x * 256 + threadIdx.x;  // float4 index, 262144 total
    const float4 v = reinterpret_cast<const float4*>(W)[i];
    ushort4 hi, lo;
    split_bf(v.x, hi.x, lo.x);
    split_bf(v.y, hi.y, lo.y);
    split_bf(v.z, hi.z, lo.z);
    split_bf(v.w, hi.w, lo.w);
    reinterpret_cast<ushort4*>(Whi)[i] = hi;
    reinterpret_cast<ushort4*>(Wlo)[i] = lo;
}

// ---------------------------------------------------------------------------
// Kernel 1: xg = emb[tokens] @ W_ih^T + bias via split-bf16 MFMA.
// (unchanged — verified)
// ---------------------------------------------------------------------------
__global__ __launch_bounds__(256)
void xg_mfma(const int* __restrict__ tokens,
             const float* __restrict__ emb,
             const ushort* __restrict__ Whi,
             const ushort* __restrict__ Wlo,
             const float* __restrict__ b_ih,
             const float* __restrict__ b_hh,
             ushort* __restrict__ xg)
{
    const int mtile = blockIdx.x;   // 0..255
    const int ntile = blockIdx.y;   // 0..15
    const int tid   = threadIdx.x;

    __shared__ ushort Ahi[128][32];
    __shared__ ushort Alo[128][32];
    __shared__ ushort Bhi[128][32];
    __shared__ ushort Blo[128][32];

    const int ar  = tid >> 3;   // 0..31
    const int seg = tid & 7;    // 0..7 -> 4-float col group
    const float* asrc[4];
    #pragma unroll
    for (int i = 0; i < 4; ++i) {
        const int m   = mtile * 128 + ar + i * 32;
        const int tok = tokens[(m & 63) * S + (m >> 6)];
        asrc[i] = emb + (size_t)tok * H + seg * 4;
    }

    const int br = tid >> 2;         // 0..63
    const int bc = (tid & 3) * 8;    // 8-ushort col group
    const ushort* bsrc_hi[2];
    const ushort* bsrc_lo[2];
    #pragma unroll
    for (int j = 0; j < 2; ++j) {
        const int n = ntile * 128 + br + j * 64;
        bsrc_hi[j] = Whi + (size_t)n * H + bc;
        bsrc_lo[j] = Wlo + (size_t)n * H + bc;
    }

    const int lane = tid & 63;
    const int wv   = tid >> 6;
    const int wr   = (wv >> 1) * 64;
    const int wc   = (wv & 1) * 64;
    const int fr   = lane & 15;
    const int ks   = lane >> 4;

    f32x4 acc[4][4];
    #pragma unroll
    for (int a = 0; a < 4; ++a)
        #pragma unroll
        for (int c = 0; c < 4; ++c)
            acc[a][c] = (f32x4){0.f, 0.f, 0.f, 0.f};

    for (int kc = 0; kc < 16; ++kc) {
        const int d0 = kc * 32;

        #pragma unroll
        for (int i = 0; i < 4; ++i) {
            const float4 v = *reinterpret_cast<const float4*>(asrc[i] + d0);
            ushort4 hi, lo;
            split_bf(v.x, hi.x, lo.x);
            split_bf(v.y, hi.y, lo.y);
            split_bf(v.z, hi.z, lo.z);
            split_bf(v.w, hi.w, lo.w);
            const int r = ar + i * 32;
            *reinterpret_cast<ushort4*>(&Ahi[r][seg * 4]) = hi;
            *reinterpret_cast<ushort4*>(&Alo[r][seg * 4]) = lo;
        }
        #pragma unroll
        for (int j = 0; j < 2; ++j) {
            const int r = br + j * 64;
            *reinterpret_cast<uint4*>(&Bhi[r][bc]) =
                *reinterpret_cast<const uint4*>(bsrc_hi[j] + d0);
            *reinterpret_cast<uint4*>(&Blo[r][bc]) =
                *reinterpret_cast<const uint4*>(bsrc_lo[j] + d0);
        }
        __syncthreads();

        bf16x8 ah[4], al[4];
        #pragma unroll
        for (int fm = 0; fm < 4; ++fm) {
            ah[fm] = *reinterpret_cast<const bf16x8*>(&Ahi[wr + fm * 16 + fr][ks * 8]);
            al[fm] = *reinterpret_cast<const bf16x8*>(&Alo[wr + fm * 16 + fr][ks * 8]);
        }
        #pragma unroll
        for (int fn = 0; fn < 4; ++fn) {
            const bf16x8 bh = *reinterpret_cast<const bf16x8*>(&Bhi[wc + fn * 16 + fr][ks * 8]);
            const bf16x8 bl = *reinterpret_cast<const bf16x8*>(&Blo[wc + fn * 16 + fr][ks * 8]);
            #pragma unroll
            for (int fm = 0; fm < 4; ++fm) {
                acc[fm][fn] = __builtin_amdgcn_mfma_f32_16x16x32_bf16(ah[fm], bh, acc[fm][fn], 0, 0, 0);
                acc[fm][fn] = __builtin_amdgcn_mfma_f32_16x16x32_bf16(al[fm], bh, acc[fm][fn], 0, 0, 0);
                acc[fm][fn] = __builtin_amdgcn_mfma_f32_16x16x32_bf16(ah[fm], bl, acc[fm][fn], 0, 0, 0);
            }
        }
        __syncthreads();
    }

    #pragma unroll
    for (int fn = 0; fn < 4; ++fn) {
        const int col  = ntile * 128 + wc + fn * 16 + fr;
        const float bias = b_ih[col] + b_hh[col];
        const int gate = col >> 9;
        const int k    = col & 511;
        const int w    = k >> 4;
        const int kl   = k & 15;
        #pragma unroll
        for (int fm = 0; fm < 4; ++fm) {
            const int row = mtile * 128 + wr + fm * 16 + ks * 4;
            const int t   = row >> 6;
            const int b   = row & 63;
            const int g   = b >> 3;
            const int b8  = b & 7;
            ushort4 us;
            us.x = f2bf(acc[fm][fn][0] + bias);
            us.y = f2bf(acc[fm][fn][1] + bias);
            us.z = f2bf(acc[fm][fn][2] + bias);
            us.w = f2bf(acc[fm][fn][3] + bias);
            const size_t idx = ((((size_t)t * 8 + g) * 32 + w) * 512) +
                               gate * 128 + kl * 8 + b8;
            *reinterpret_cast<ushort4*>(&xg[idx]) = us;
        }
    }
}

// ---------------------------------------------------------------------------
// Kernel 1 (old, mid-tier fallback): f32 vector GEMM. Unchanged.
// ---------------------------------------------------------------------------
__global__ __launch_bounds__(256)
void xg_gemm(const int* __restrict__ tokens,
             const float* __restrict__ emb,
             const float* __restrict__ W_ih,
             const float* __restrict__ b_ih,
             const float* __restrict__ b_hh,
             ushort* __restrict__ xg)
{
    const int t      = blockIdx.x;
    const int g_base = blockIdx.y * 128;
    const int tid    = threadIdx.x;

    const int b_ld = tid >> 2;
    const int seg  = tid & 3;
    const int r_w  = tid >> 1;
    const int half = tid & 1;
    const int b0 = (tid & 15) * 4;
    const int g0 = (tid >> 4) * 8;

    const int token = tokens[b_ld * S + t];
    const float4* embrow = reinterpret_cast<const float4*>(emb) + (size_t)token * (H / 4);

    __shared__ float hs[64][64];
    __shared__ float ws[128][68];

    float acc[4][8];
    #pragma unroll
    for (int i = 0; i < 4; ++i)
        #pragma unroll
        for (int j = 0; j < 8; ++j) acc[i][j] = 0.0f;

    for (int kc = 0; kc < 8; ++kc) {
        const int d0 = kc * 64;
        #pragma unroll
        for (int i = 0; i < 4; ++i) {
            const int dl = seg * 16 + i * 4;
            const float4 f = embrow[(d0 >> 2) + seg * 4 + i];
            hs[dl + 0][b_ld] = f.x;
            hs[dl + 1][b_ld] = f.y;
            hs[dl + 2][b_ld] = f.z;
            hs[dl + 3][b_ld] = f.w;
        }
        const float4* wrow = reinterpret_cast<const float4*>(W_ih) +
                             (size_t)(g_base + r_w) * (H / 4) + (d0 >> 2) + half * 8;
        #pragma unroll
        for (int i = 0; i < 8; ++i) {
            *reinterpret_cast<float4*>(&ws[r_w][half * 32 + i * 4]) = wrow[i];
        }
        __syncthreads();

        #pragma unroll
        for (int d4 = 0; d4 < 16; ++d4) {
            const float4 hv0 = *reinterpret_cast<const float4*>(&hs[d4 * 4 + 0][b0]);
            const float4 hv1 = *reinterpret_cast<const float4*>(&hs[d4 * 4 + 1][b0]);
            const float4 hv2 = *reinterpret_cast<const float4*>(&hs[d4 * 4 + 2][b0]);
            const float4 hv3 = *reinterpret_cast<const float4*>(&hs[d4 * 4 + 3][b0]);
            #pragma unroll
            for (int gg = 0; gg < 8; ++gg) {
                const float4 w = *reinterpret_cast<const float4*>(&ws[g0 + gg][d4 * 4]);
                acc[0][gg] += hv0.x * w.x + hv1.x * w.y + hv2.x * w.z + hv3.x * w.w;
                acc[1][gg] += hv0.y * w.x + hv1.y * w.y + hv2.y * w.z + hv3.y * w.w;
                acc[2][gg] += hv0.z * w.x + hv1.z * w.y + hv2.z * w.z + hv3.z * w.w;
                acc[3][gg] += hv0.w * w.x + hv1.w * w.y + hv2.w * w.z + hv3.w * w.w;
            }
        }
        __syncthreads();
    }

    const int grp = b0 >> 3;
    const int b8l = b0 & 7;
    #pragma unroll
    for (int gg = 0; gg < 8; ++gg) {
        const int gcol = g_base + g0 + gg;
        const int gate = gcol >> 9;
        const int k    = gcol & 511;
        const int w    = k >> 4;
        const int kl   = k & 15;
        const float bias = b_ih[gcol] + b_hh[gcol];
        ushort4 us;
        us.x = f2bf(acc[0][gg] + bias);
        us.y = f2bf(acc[1][gg] + bias);
        us.z = f2bf(acc[2][gg] + bias);
        us.w = f2bf(acc[3][gg] + bias);
        const size_t idx = ((((size_t)t * 8 + grp) * 32 + w) * 512) +
                           gate * 128 + kl * 8 + b8l;
        *reinterpret_cast<ushort4*>(&xg[idx]) = us;
    }
}

#define GSTR 4096          // 8 b * 512 d floats per group (f32 fallback layout)
#define PSTR 32768         // per parity: 8 groups * GSTR (f32 fallback layout)
#define HQ3P 32768         // uints per rotation buffer: 8 groups * 4096
#define SENT 0xFFFFFFFFu   // NaN|NaN packed -- unreachable for tanh-bounded h

// ---------------------------------------------------------------------------
// Kernel 2: persistent LSTM recurrence, split-bf16 MFMA + SELF-SIGNALING
// sentinel exchange (no flags, no arrival barrier):
//  * h exchanged as ONE packed 4B uint (bf16hi<<16 | bf16lo). Dword stores
//    (R4's 2B-store pathology avoided). Consumer unpacks via 2 v_perm per 8B.
//  * consumer stage-loads ARE the sync: re-poll any word == SENT.
//  * 3 rotating buffers; each wg sentinel-resets its 512B partition of
//    buf[(t+2)%3] each step. vmcnt(0) before the h store orders resets
//    ahead of h publication (transitively: resets precede next writer).
//  * one __syncthreads per step; LDS double-buffered (2 x 16 KB).
// MFMA loop / A-fragments / swizzle byte-identical to verified R2 kernel.
// ---------------------------------------------------------------------------
__global__ __launch_bounds__(256)
__attribute__((amdgpu_waves_per_eu(1, 1)))
void lstm_persist_mfma4(const ushort* __restrict__ Whh_hi,
                        const ushort* __restrict__ Whh_lo,
                        const ushort* __restrict__ xg,
                        unsigned int* __restrict__ hq3,   // [3][8][8*512] packed
                        float* __restrict__ out)
{
    const int tid  = threadIdx.x;
    const int g    = blockIdx.x & 7;
    const int w    = blockIdx.x >> 3;
    const int k0   = w * 16;
    const int lane = tid & 63;
    const int wv   = tid >> 6;

    // per-lane output mapping
    const int  bcol   = lane & 15;              // batch col (valid < 8)
    const int  klane  = 4 * wv + (lane >> 4);   // k within wg's 16
    const bool active = bcol < 8;
    const int  b8     = lane & 7;

    const ushort* xg_wg = xg + (((size_t)g * 32 + w) * 512);

    // ---- A-fragments: W_hh split planes, held in regs for all 512 steps ----
    const int ar    = lane & 15;
    const int agate = ar & 3;
    const int ak    = k0 + 4 * wv + (ar >> 2);
    const size_t arow = ((size_t)agate * 512 + ak) * 512 + (size_t)(lane >> 4) * 8;
    bf16x8 afh[16], afl[16];
    #pragma unroll
    for (int ks = 0; ks < 16; ++ks) {
        afh[ks] = *reinterpret_cast<const bf16x8*>(Whh_hi + arow + ks * 32);
        afl[ks] = *reinterpret_cast<const bf16x8*>(Whh_lo + arow + ks * 32);
    }

    // LDS: 2 parities x { hi 8KB | lo 8KB }
    __shared__ __align__(16) char hsB[2 * 16384];

    float c_reg = 0.0f;

    float xv_cur[4] = {0.f, 0.f, 0.f, 0.f};
    if (active) {
        #pragma unroll
        for (int gate = 0; gate < 4; ++gate)
            xv_cur[gate] = bf2f(xg_wg[gate * 128 + klane * 8 + b8]);
    }

    unsigned int rot = 0;   // t % 3

    for (int t = 0; t < S; ++t) {
        const unsigned int wrot = (rot + 1 == 3) ? 0 : rot + 1;
        const unsigned int rrot = (wrot + 1 == 3) ? 0 : wrot + 1;

        // ---- stage-with-poll: 8 x 8B loads; re-poll sentinel words ----
        const unsigned long long* hsrc = reinterpret_cast<const unsigned long long*>(
            hq3 + (size_t)rot * HQ3P + g * 4096);
        unsigned long long hv[8];
        bool stale[8];
        #pragma unroll
        for (int i = 0; i < 8; ++i) {
            hv[i] = __hip_atomic_load(&hsrc[i * 256 + tid],
                                      __ATOMIC_RELAXED, __HIP_MEMORY_SCOPE_AGENT);
            stale[i] = ((unsigned int)hv[i] == SENT) ||
                       ((unsigned int)(hv[i] >> 32) == SENT);
        }
        for (;;) {
            bool any = false;
            #pragma unroll
            for (int i = 0; i < 8; ++i) any |= stale[i];
            if (!__any(any)) break;
            __builtin_amdgcn_s_sleep(1);
            #pragma unroll
            for (int i = 0; i < 8; ++i) {
                if (stale[i]) {
                    hv[i] = __hip_atomic_load(&hsrc[i * 256 + tid],
                                              __ATOMIC_RELAXED, __HIP_MEMORY_SCOPE_AGENT);
                    stale[i] = ((unsigned int)hv[i] == SENT) ||
                               ((unsigned int)(hv[i] >> 32) == SENT);
                }
            }
        }

        // ---- unpack (2 v_perm / 8B) -> swizzled hi/lo LDS planes ----
        const int pbase = (t & 1) << 14;
        #pragma unroll
        for (int i = 0; i < 8; ++i) {
            const int e  = 2 * (i * 256 + tid);
            const int bb = e >> 9;
            const int dd = e & 511;          // even
            const unsigned int u0 = (unsigned int)hv[i];
            const unsigned int u1 = (unsigned int)(hv[i] >> 32);
            const unsigned int hiw = __builtin_amdgcn_perm(u1, u0, 0x07060302u);
            const unsigned int low = __builtin_amdgcn_perm(u1, u0, 0x05040100u);
            const int byteoff = (((bb << 10) + (dd << 1)) ^ (bb << 4)) + pbase;
            *reinterpret_cast<unsigned int*>(hsB + byteoff) = hiw;
            *reinterpret_cast<unsigned int*>(hsB + 8192 + byteoff) = low;
        }
        __syncthreads();

        // ---- sentinel-reset this wg's partition of buf[(t+2)%3] ----
        // Safe: observing all h_t fresh => every wg's step t-1 reads retired.
        if (tid < 128)
            __hip_atomic_store(hq3 + (size_t)rrot * HQ3P + g * 4096 + w * 128 + tid,
                               SENT, __ATOMIC_RELAXED, __HIP_MEMORY_SCOPE_AGENT);

        // ---- prefetch xg for t+1 (overlaps MFMA) ----
        float xv_nxt[4] = {0.f, 0.f, 0.f, 0.f};
        if (active && t + 1 < S) {
            const ushort* p = xg_wg + (size_t)(t + 1) * (8 * 32 * 512);
            #pragma unroll
            for (int gate = 0; gate < 4; ++gate)
                xv_nxt[gate] = bf2f(p[gate * 128 + klane * 8 + b8]);
        }

        // ---- MFMA: 16 K-steps x 3 products, 6 rotating accumulators ----
        f32x4 a0 = (f32x4){0.f,0.f,0.f,0.f}, a1 = a0, a2 = a0, a3 = a0, a4 = a0, a5 = a0;
        #pragma unroll
        for (int ks = 0; ks < 16; ++ks) {
            const int kbyte = ((((b8 << 10) + ((ks * 32 + (lane >> 4) * 8) << 1)) ^ (b8 << 4))) + pbase;
            const bf16x8 bh = *reinterpret_cast<const bf16x8*>(hsB + kbyte);
            const bf16x8 bl = *reinterpret_cast<const bf16x8*>(hsB + 8192 + kbyte);
            if (ks & 1) {
                a1 = __builtin_amdgcn_mfma_f32_16x16x32_bf16(afh[ks], bh, a1, 0, 0, 0);
                a3 = __builtin_amdgcn_mfma_f32_16x16x32_bf16(afl[ks], bh, a3, 0, 0, 0);
                a5 = __builtin_amdgcn_mfma_f32_16x16x32_bf16(afh[ks], bl, a5, 0, 0, 0);
            } else {
                a0 = __builtin_amdgcn_mfma_f32_16x16x32_bf16(afh[ks], bh, a0, 0, 0, 0);
                a2 = __builtin_amdgcn_mfma_f32_16x16x32_bf16(afl[ks], bh, a2, 0, 0, 0);
                a4 = __builtin_amdgcn_mfma_f32_16x16x32_bf16(afh[ks], bl, a4, 0, 0, 0);
            }
        }
        const f32x4 acc = (a0 + a1) + ((a2 + a3) + (a4 + a5));

        // ---- per-lane gate combine + h/c update ----
        float hn = 0.0f, cn = 0.0f;
        ushort hh = 0, hl = 0;
        if (active) {
            const float ig = sigmoidf_(acc[0] + xv_cur[0]);
            const float fg = sigmoidf_(acc[1] + xv_cur[1]);
            const float gg = tanhf_(acc[2] + xv_cur[2]);
            const float og = sigmoidf_(acc[3] + xv_cur[3]);
            cn = fg * c_reg + ig * gg;
            c_reg = cn;
            hn = og * tanhf_(cn);
            split_bf(hn, hh, hl);
        }

        // ---- order resets (and everything) before h publication ----
        asm volatile("s_waitcnt vmcnt(0)" ::: "memory");
        if (active)
            __hip_atomic_store(hq3 + (size_t)wrot * HQ3P + g * 4096 + b8 * 512 + k0 + klane,
                               ((unsigned int)hh << 16) | (unsigned int)hl,
                               __ATOMIC_RELAXED, __HIP_MEMORY_SCOPE_AGENT);

        // ---- deferred out stores (off the exchange critical path) ----
        if (active) {
            out[((size_t)(g * 8 + b8) * S + t) * H + k0 + klane] = hn;
            if (t == S - 1) {
                const size_t OFF = (size_t)B * S * H;
                out[OFF + (size_t)(g * 8 + b8) * H + k0 + klane] = hn;
                out[OFF + (size_t)B * H + (size_t)(g * 8 + b8) * H + k0 + klane] = cn;
            }
        }

        xv_cur[0] = xv_nxt[0]; xv_cur[1] = xv_nxt[1];
        xv_cur[2] = xv_nxt[2]; xv_cur[3] = xv_nxt[3];
        rot = wrot;
    }
}

// ---------------------------------------------------------------------------
// Kernel 2 (old, fallback tier): vector-FMA persistent recurrence. Unchanged.
// ---------------------------------------------------------------------------
__global__ __launch_bounds__(256)
__attribute__((amdgpu_waves_per_eu(1, 1)))
void lstm_persist(const float* __restrict__ W_hh,
                  const ushort* __restrict__ xg,
                  float* __restrict__ hq,
                  unsigned int* __restrict__ bar,
                  float* __restrict__ out)
{
    const int tid = threadIdx.x;
    const int g   = blockIdx.x & 7;
    const int w   = blockIdx.x >> 3;
    const int k0  = w * 16;

    const int rp = tid & 31;
    const int d8 = tid >> 5;
    const int d0 = d8 * 64;

    const int b8 = tid >> 4;
    const int kl = tid & 15;

    unsigned int* bcnt = bar + g * 64;

    const ushort* xg_wg = xg + (((size_t)g * 32 + w) * 512);

    float4 wreg[2][16];
    #pragma unroll
    for (int r = 0; r < 2; ++r) {
        const int rl = 2 * rp + r;
        const int grow = (rl >> 4) * H + k0 + (rl & 15);
        const float4* wp = reinterpret_cast<const float4*>(W_hh + (size_t)grow * H + d0);
        #pragma unroll
        for (int i = 0; i < 16; ++i) wreg[r][i] = wp[i];
    }

    __shared__ float hs[8 * 512];
    __shared__ float part[8 * 8 * 64];

    float c_reg = 0.0f;

    float xv_cur[4] = {0.f, 0.f, 0.f, 0.f};
    if (tid < 128) {
        #pragma unroll
        for (int gate = 0; gate < 4; ++gate)
            xv_cur[gate] = bf2f(xg_wg[gate * 128 + kl * 8 + b8]);
    }

    for (int t = 0; t < S; ++t) {
        const unsigned long long* hsrc8 = reinterpret_cast<const unsigned long long*>(
            hq + (t & 1) * PSTR + g * GSTR);
        #pragma unroll
        for (int i = 0; i < 8; ++i) {
            const unsigned long long v = __hip_atomic_load(&hsrc8[i * 256 + tid],
                                                           __ATOMIC_RELAXED,
                                                           __HIP_MEMORY_SCOPE_AGENT);
            reinterpret_cast<unsigned long long*>(hs)[i * 256 + tid] = v;
        }
        __syncthreads();

        float xv_nxt[4] = {0.f, 0.f, 0.f, 0.f};
        if (tid < 128 && t + 1 < S) {
            const ushort* p = xg_wg + (size_t)(t + 1) * (8 * 32 * 512);
            #pragma unroll
            for (int gate = 0; gate < 4; ++gate)
                xv_nxt[gate] = bf2f(p[gate * 128 + kl * 8 + b8]);
        }

        float acc[2][8];
        #pragma unroll
        for (int r = 0; r < 2; ++r)
            #pragma unroll
            for (int b = 0; b < 8; ++b) acc[r][b] = 0.0f;

        #pragma unroll
        for (int b = 0; b < 8; ++b) {
            const float4* h4 = reinterpret_cast<const float4*>(hs + b * 512 + d0);
            #pragma unroll
            for (int i = 0; i < 16; ++i) {
                const float4 hv = h4[i];
                acc[0][b] += wreg[0][i].x * hv.x + wreg[0][i].y * hv.y +
                             wreg[0][i].z * hv.z + wreg[0][i].w * hv.w;
                acc[1][b] += wreg[1][i].x * hv.x + wreg[1][i].y * hv.y +
                             wreg[1][i].z * hv.z + wreg[1][i].w * hv.w;
            }
        }

        #pragma unroll
        for (int r = 0; r < 2; ++r)
            #pragma unroll
            for (int b = 0; b < 8; ++b)
                part[d8 * 512 + b * 64 + 2 * rp + r] = acc[r][b];
        __syncthreads();

        if (tid < 128) {
            float v[4];
            #pragma unroll
            for (int gate = 0; gate < 4; ++gate) {
                const int rl = gate * 16 + kl;
                float s = 0.0f;
                #pragma unroll
                for (int q = 0; q < 8; ++q) s += part[q * 512 + b8 * 64 + rl];
                v[gate] = s + xv_cur[gate];
            }
            const float ig = sigmoidf_(v[0]);
            const float fg = sigmoidf_(v[1]);
            const float gg = tanhf_(v[2]);
            const float og = sigmoidf_(v[3]);

            const float cn = fg * c_reg + ig * gg;
            c_reg = cn;
            const float hn = og * tanhf_(cn);

            __hip_atomic_store(&hq[((t & 1) ^ 1) * PSTR + g * GSTR + b8 * 512 + k0 + kl],
                               hn, __ATOMIC_RELAXED, __HIP_MEMORY_SCOPE_AGENT);
            out[((size_t)(g * 8 + b8) * S + t) * H + k0 + kl] = hn;
            if (t == S - 1) {
                const size_t OFF = (size_t)B * S * H;
                out[OFF + (size_t)(g * 8 + b8) * H + k0 + kl] = hn;
                out[OFF + (size_t)B * H + (size_t)(g * 8 + b8) * H + k0 + kl] = cn;
            }
        }

        __syncthreads();
        if (tid == 0) {
            __hip_atomic_fetch_add(bcnt, 1u, __ATOMIC_RELAXED,
                                   __HIP_MEMORY_SCOPE_AGENT);
            const unsigned int target = 32u * (unsigned int)(t + 1);
            while (__hip_atomic_load(bcnt, __ATOMIC_RELAXED,
                                     __HIP_MEMORY_SCOPE_AGENT) < target)
                __builtin_amdgcn_s_sleep(2);
        }
        __syncthreads();

        xv_cur[0] = xv_nxt[0]; xv_cur[1] = xv_nxt[1];
        xv_cur[2] = xv_nxt[2]; xv_cur[3] = xv_nxt[3];
    }
}

// ---------------------------------------------------------------------------
// Fallback (round-2 path) if ws_size is too small.
// ---------------------------------------------------------------------------
__global__ __launch_bounds__(128)
void lstm_step_fb(const int* __restrict__ tokens,
                  const float* __restrict__ emb,
                  const float* __restrict__ W_ih,
                  const float* __restrict__ W_hh,
                  const float* __restrict__ b_ih,
                  const float* __restrict__ b_hh,
                  const float* __restrict__ h_prev,
                  float* __restrict__ h_next,
                  float* __restrict__ c_st,
                  float* __restrict__ out,
                  int t)
{
    const int tid = threadIdx.x;
    const int b   = tid & 63;
    const int k   = blockIdx.x * 2 + (tid >> 6);
    const int token = tokens[b * S + t];
    const float* xrow = emb + (size_t)token * H;
    const float* hrow = h_prev + b * H;
    float acc[4];
    #pragma unroll
    for (int g = 0; g < 4; ++g) acc[g] = b_ih[g * H + k] + b_hh[g * H + k];
    for (int d = 0; d < H; ++d) {
        const float xv = xrow[d], hv = hrow[d];
        #pragma unroll
        for (int g = 0; g < 4; ++g)
            acc[g] += xv * W_ih[(size_t)(g * H + k) * H + d] + hv * W_hh[(size_t)(g * H + k) * H + d];
    }
    const float ig = sigmoidf_(acc[0]);
    const float fg = sigmoidf_(acc[1]);
    const float gg = tanhf(acc[2]);
    const float og = sigmoidf_(acc[3]);
    const int ck = b * H + k;
    const float cn = fg * c_st[ck] + ig * gg;
    c_st[ck] = cn;
    const float hn = og * tanhf(cn);
    h_next[ck] = hn;
    out[(size_t)b * S * H + (size_t)t * H + k] = hn;
    if (t == S - 1) {
        out[(size_t)B * S * H + ck] = hn;
        out[(size_t)B * S * H + B * H + ck] = cn;
    }
}

extern "C" void kernel_launch(void* const* d_in, const int* in_sizes, int n_in,
                              void* d_out, int out_size, void* d_ws, size_t ws_size,
                              hipStream_t stream)
{
    const int*   tokens = (const int*)d_in[0];
    const float* emb    = (const float*)d_in[1];
    const float* W_ih   = (const float*)d_in[2];
    const float* W_hh   = (const float*)d_in[3];
    const float* b_ih   = (const float*)d_in[4];
    const float* b_hh   = (const float*)d_in[5];
    float* out = (float*)d_out;

    const size_t XG_BYTES   = (size_t)S * G4 * B * 2;       // 134217728
    const size_t HQ3_BYTES  = (size_t)3 * HQ3P * 4;         // 393216 (3 rot bufs)
    const size_t HQ_BYTES   = (size_t)2 * PSTR * 4;         // 262144 (legacy)
    const size_t FLAG_BYTES = 16384;                        // legacy bar area
    const size_t W_BYTES    = (size_t)G4 * H * 2;           // 2 MB per bf16 plane
    const size_t NEED_OLD   = XG_BYTES + HQ_BYTES + FLAG_BYTES;
    const size_t NEED_R1    = NEED_OLD + 2 * W_BYTES;       // + Wih hi/lo
    const size_t NEED_R3    = XG_BYTES + HQ3_BYTES + 4 * W_BYTES;

    if (ws_size >= NEED_R3) {
        ushort* xg = (ushort*)d_ws;
        unsigned int* hq3 = (unsigned int*)((char*)d_ws + XG_BYTES);
        ushort* Wih_hi = (ushort*)((char*)d_ws + XG_BYTES + HQ3_BYTES);
        ushort* Wih_lo = Wih_hi + (size_t)G4 * H;
        ushort* Whh_hi = Wih_lo + (size_t)G4 * H;
        ushort* Whh_lo = Whh_hi + (size_t)G4 * H;

        // buf0 = packed zeros (h_0 = 0); buf1,2 = sentinel
        (void)hipMemsetAsync(hq3, 0x00, (size_t)HQ3P * 4, stream);
        (void)hipMemsetAsync((char*)hq3 + (size_t)HQ3P * 4, 0xFF,
                             (size_t)2 * HQ3P * 4, stream);

        w_split<<<dim3((G4 * H / 4) / 256), dim3(256), 0, stream>>>(W_ih, Wih_hi, Wih_lo);
        w_split<<<dim3((G4 * H / 4) / 256), dim3(256), 0, stream>>>(W_hh, Whh_hi, Whh_lo);

        xg_mfma<<<dim3(256, 16), dim3(256), 0, stream>>>(
            tokens, emb, Wih_hi, Wih_lo, b_ih, b_hh, xg);

        lstm_persist_mfma4<<<dim3(256), dim3(256), 0, stream>>>(
            Whh_hi, Whh_lo, xg, hq3, out);
    } else if (ws_size >= NEED_R1) {
        ushort* xg = (ushort*)d_ws;
        float*  hq = (float*)((char*)d_ws + XG_BYTES);
        unsigned int* bar = (unsigned int*)((char*)d_ws + XG_BYTES + HQ_BYTES);
        ushort* Wih_hi = (ushort*)((char*)d_ws + NEED_OLD);
        ushort* Wih_lo = Wih_hi + (size_t)G4 * H;

        (void)hipMemsetAsync(hq, 0, HQ_BYTES + FLAG_BYTES, stream);

        w_split<<<dim3((G4 * H / 4) / 256), dim3(256), 0, stream>>>(W_ih, Wih_hi, Wih_lo);

        xg_mfma<<<dim3(256, 16), dim3(256), 0, stream>>>(
            tokens, emb, Wih_hi, Wih_lo, b_ih, b_hh, xg);

        lstm_persist<<<dim3(256), dim3(256), 0, stream>>>(W_hh, xg, hq, bar, out);
    } else if (ws_size >= NEED_OLD) {
        ushort* xg = (ushort*)d_ws;
        float*  hq = (float*)((char*)d_ws + XG_BYTES);
        unsigned int* bar = (unsigned int*)((char*)d_ws + XG_BYTES + HQ_BYTES);

        (void)hipMemsetAsync(hq, 0, HQ_BYTES + FLAG_BYTES, stream);

        xg_gemm<<<dim3(S, 16), dim3(256), 0, stream>>>(tokens, emb, W_ih, b_ih, b_hh, xg);

        lstm_persist<<<dim3(256), dim3(256), 0, stream>>>(W_hh, xg, hq, bar, out);
    } else {
        float* c_st = (float*)d_ws;
        float* h0   = c_st + B * H;
        float* h1   = h0 + B * H;
        (void)hipMemsetAsync(d_ws, 0, (size_t)3 * B * H * sizeof(float), stream);
        for (int t = 0; t < S; ++t) {
            const float* hp = (t & 1) ? h1 : h0;
            float*       hn = (t & 1) ? h0 : h1;
            lstm_step_fb<<<dim3(256), dim3(128), 0, stream>>>(
                tokens, emb, W_ih, W_hh, b_ih, b_hh, hp, hn, c_st, out, t);
        }
    }
}

// Round 7
// 3323.704 us; speedup vs baseline: 1.0151x; 1.0151x over previous
//
#include <hip/hip_runtime.h>
#include <math.h>

#define B 64
#define S 512
#define H 512
#define G4 2048  // 4*H gate columns

typedef __attribute__((ext_vector_type(8))) short bf16x8;
typedef __attribute__((ext_vector_type(4))) float f32x4;

__device__ __forceinline__ float sigmoidf_(float x) {
    return 1.0f / (1.0f + __expf(-x));
}
__device__ __forceinline__ float tanhf_(float x) {
    return 2.0f / (1.0f + __expf(-2.0f * x)) - 1.0f;
}

// bf16 <-> f32 via raw bits (RNE)
__device__ __forceinline__ ushort f2bf(float f) {
    union { float f; unsigned int u; } v; v.f = f;
    unsigned int r = v.u + 0x7FFFu + ((v.u >> 16) & 1u);
    return (ushort)(r >> 16);
}
__device__ __forceinline__ float bf2f(ushort s) {
    union { unsigned int u; float f; } v; v.u = ((unsigned int)s) << 16;
    return v.f;
}
// split f32 into bf16 hi + bf16 lo, x ~= hi + lo to ~2^-18 rel
__device__ __forceinline__ void split_bf(float x, ushort& hi, ushort& lo) {
    const ushort h = f2bf(x);
    hi = h;
    lo = f2bf(x - bf2f(h));
}

// ---------------------------------------------------------------------------
// Pre-pass: split a f32 [2048][512] weight into bf16 hi/lo planes, once.
// ---------------------------------------------------------------------------
__global__ __launch_bounds__(256)
void w_split(const float* __restrict__ W,
             ushort* __restrict__ Whi,
             ushort* __restrict__ Wlo)
{
    const int i = blockIdx.x * 256 + threadIdx.x;  // float4 index, 262144 total
    const float4 v = reinterpret_cast<const float4*>(W)[i];
    ushort4 hi, lo;
    split_bf(v.x, hi.x, lo.x);
    split_bf(v.y, hi.y, lo.y);
    split_bf(v.z, hi.z, lo.z);
    split_bf(v.w, hi.w, lo.w);
    reinterpret_cast<ushort4*>(Whi)[i] = hi;
    reinterpret_cast<ushort4*>(Wlo)[i] = lo;
}

// ---------------------------------------------------------------------------
// Kernel 1: xg = emb[tokens] @ W_ih^T + bias via split-bf16 MFMA.
// (unchanged — verified)
// ---------------------------------------------------------------------------
__global__ __launch_bounds__(256)
void xg_mfma(const int* __restrict__ tokens,
             const float* __restrict__ emb,
             const ushort* __restrict__ Whi,
             const ushort* __restrict__ Wlo,
             const float* __restrict__ b_ih,
             const float* __restrict__ b_hh,
             ushort* __restrict__ xg)
{
    const int mtile = blockIdx.x;   // 0..255
    const int ntile = blockIdx.y;   // 0..15
    const int tid   = threadIdx.x;

    __shared__ ushort Ahi[128][32];
    __shared__ ushort Alo[128][32];
    __shared__ ushort Bhi[128][32];
    __shared__ ushort Blo[128][32];

    const int ar  = tid >> 3;   // 0..31
    const int seg = tid & 7;    // 0..7 -> 4-float col group
    const float* asrc[4];
    #pragma unroll
    for (int i = 0; i < 4; ++i) {
        const int m   = mtile * 128 + ar + i * 32;
        const int tok = tokens[(m & 63) * S + (m >> 6)];
        asrc[i] = emb + (size_t)tok * H + seg * 4;
    }

    const int br = tid >> 2;         // 0..63
    const int bc = (tid & 3) * 8;    // 8-ushort col group
    const ushort* bsrc_hi[2];
    const ushort* bsrc_lo[2];
    #pragma unroll
    for (int j = 0; j < 2; ++j) {
        const int n = ntile * 128 + br + j * 64;
        bsrc_hi[j] = Whi + (size_t)n * H + bc;
        bsrc_lo[j] = Wlo + (size_t)n * H + bc;
    }

    const int lane = tid & 63;
    const int wv   = tid >> 6;
    const int wr   = (wv >> 1) * 64;
    const int wc   = (wv & 1) * 64;
    const int fr   = lane & 15;
    const int ks   = lane >> 4;

    f32x4 acc[4][4];
    #pragma unroll
    for (int a = 0; a < 4; ++a)
        #pragma unroll
        for (int c = 0; c < 4; ++c)
            acc[a][c] = (f32x4){0.f, 0.f, 0.f, 0.f};

    for (int kc = 0; kc < 16; ++kc) {
        const int d0 = kc * 32;

        #pragma unroll
        for (int i = 0; i < 4; ++i) {
            const float4 v = *reinterpret_cast<const float4*>(asrc[i] + d0);
            ushort4 hi, lo;
            split_bf(v.x, hi.x, lo.x);
            split_bf(v.y, hi.y, lo.y);
            split_bf(v.z, hi.z, lo.z);
            split_bf(v.w, hi.w, lo.w);
            const int r = ar + i * 32;
            *reinterpret_cast<ushort4*>(&Ahi[r][seg * 4]) = hi;
            *reinterpret_cast<ushort4*>(&Alo[r][seg * 4]) = lo;
        }
        #pragma unroll
        for (int j = 0; j < 2; ++j) {
            const int r = br + j * 64;
            *reinterpret_cast<uint4*>(&Bhi[r][bc]) =
                *reinterpret_cast<const uint4*>(bsrc_hi[j] + d0);
            *reinterpret_cast<uint4*>(&Blo[r][bc]) =
                *reinterpret_cast<const uint4*>(bsrc_lo[j] + d0);
        }
        __syncthreads();

        bf16x8 ah[4], al[4];
        #pragma unroll
        for (int fm = 0; fm < 4; ++fm) {
            ah[fm] = *reinterpret_cast<const bf16x8*>(&Ahi[wr + fm * 16 + fr][ks * 8]);
            al[fm] = *reinterpret_cast<const bf16x8*>(&Alo[wr + fm * 16 + fr][ks * 8]);
        }
        #pragma unroll
        for (int fn = 0; fn < 4; ++fn) {
            const bf16x8 bh = *reinterpret_cast<const bf16x8*>(&Bhi[wc + fn * 16 + fr][ks * 8]);
            const bf16x8 bl = *reinterpret_cast<const bf16x8*>(&Blo[wc + fn * 16 + fr][ks * 8]);
            #pragma unroll
            for (int fm = 0; fm < 4; ++fm) {
                acc[fm][fn] = __builtin_amdgcn_mfma_f32_16x16x32_bf16(ah[fm], bh, acc[fm][fn], 0, 0, 0);
                acc[fm][fn] = __builtin_amdgcn_mfma_f32_16x16x32_bf16(al[fm], bh, acc[fm][fn], 0, 0, 0);
                acc[fm][fn] = __builtin_amdgcn_mfma_f32_16x16x32_bf16(ah[fm], bl, acc[fm][fn], 0, 0, 0);
            }
        }
        __syncthreads();
    }

    #pragma unroll
    for (int fn = 0; fn < 4; ++fn) {
        const int col  = ntile * 128 + wc + fn * 16 + fr;
        const float bias = b_ih[col] + b_hh[col];
        const int gate = col >> 9;
        const int k    = col & 511;
        const int w    = k >> 4;
        const int kl   = k & 15;
        #pragma unroll
        for (int fm = 0; fm < 4; ++fm) {
            const int row = mtile * 128 + wr + fm * 16 + ks * 4;
            const int t   = row >> 6;
            const int b   = row & 63;
            const int g   = b >> 3;
            const int b8  = b & 7;
            ushort4 us;
            us.x = f2bf(acc[fm][fn][0] + bias);
            us.y = f2bf(acc[fm][fn][1] + bias);
            us.z = f2bf(acc[fm][fn][2] + bias);
            us.w = f2bf(acc[fm][fn][3] + bias);
            const size_t idx = ((((size_t)t * 8 + g) * 32 + w) * 512) +
                               gate * 128 + kl * 8 + b8;
            *reinterpret_cast<ushort4*>(&xg[idx]) = us;
        }
    }
}

// ---------------------------------------------------------------------------
// Kernel 1 (old, mid-tier fallback): f32 vector GEMM. Unchanged.
// ---------------------------------------------------------------------------
__global__ __launch_bounds__(256)
void xg_gemm(const int* __restrict__ tokens,
             const float* __restrict__ emb,
             const float* __restrict__ W_ih,
             const float* __restrict__ b_ih,
             const float* __restrict__ b_hh,
             ushort* __restrict__ xg)
{
    const int t      = blockIdx.x;
    const int g_base = blockIdx.y * 128;
    const int tid    = threadIdx.x;

    const int b_ld = tid >> 2;
    const int seg  = tid & 3;
    const int r_w  = tid >> 1;
    const int half = tid & 1;
    const int b0 = (tid & 15) * 4;
    const int g0 = (tid >> 4) * 8;

    const int token = tokens[b_ld * S + t];
    const float4* embrow = reinterpret_cast<const float4*>(emb) + (size_t)token * (H / 4);

    __shared__ float hs[64][64];
    __shared__ float ws[128][68];

    float acc[4][8];
    #pragma unroll
    for (int i = 0; i < 4; ++i)
        #pragma unroll
        for (int j = 0; j < 8; ++j) acc[i][j] = 0.0f;

    for (int kc = 0; kc < 8; ++kc) {
        const int d0 = kc * 64;
        #pragma unroll
        for (int i = 0; i < 4; ++i) {
            const int dl = seg * 16 + i * 4;
            const float4 f = embrow[(d0 >> 2) + seg * 4 + i];
            hs[dl + 0][b_ld] = f.x;
            hs[dl + 1][b_ld] = f.y;
            hs[dl + 2][b_ld] = f.z;
            hs[dl + 3][b_ld] = f.w;
        }
        const float4* wrow = reinterpret_cast<const float4*>(W_ih) +
                             (size_t)(g_base + r_w) * (H / 4) + (d0 >> 2) + half * 8;
        #pragma unroll
        for (int i = 0; i < 8; ++i) {
            *reinterpret_cast<float4*>(&ws[r_w][half * 32 + i * 4]) = wrow[i];
        }
        __syncthreads();

        #pragma unroll
        for (int d4 = 0; d4 < 16; ++d4) {
            const float4 hv0 = *reinterpret_cast<const float4*>(&hs[d4 * 4 + 0][b0]);
            const float4 hv1 = *reinterpret_cast<const float4*>(&hs[d4 * 4 + 1][b0]);
            const float4 hv2 = *reinterpret_cast<const float4*>(&hs[d4 * 4 + 2][b0]);
            const float4 hv3 = *reinterpret_cast<const float4*>(&hs[d4 * 4 + 3][b0]);
            #pragma unroll
            for (int gg = 0; gg < 8; ++gg) {
                const float4 w = *reinterpret_cast<const float4*>(&ws[g0 + gg][d4 * 4]);
                acc[0][gg] += hv0.x * w.x + hv1.x * w.y + hv2.x * w.z + hv3.x * w.w;
                acc[1][gg] += hv0.y * w.x + hv1.y * w.y + hv2.y * w.z + hv3.y * w.w;
                acc[2][gg] += hv0.z * w.x + hv1.z * w.y + hv2.z * w.z + hv3.z * w.w;
                acc[3][gg] += hv0.w * w.x + hv1.w * w.y + hv2.w * w.z + hv3.w * w.w;
            }
        }
        __syncthreads();
    }

    const int grp = b0 >> 3;
    const int b8l = b0 & 7;
    #pragma unroll
    for (int gg = 0; gg < 8; ++gg) {
        const int gcol = g_base + g0 + gg;
        const int gate = gcol >> 9;
        const int k    = gcol & 511;
        const int w    = k >> 4;
        const int kl   = k & 15;
        const float bias = b_ih[gcol] + b_hh[gcol];
        ushort4 us;
        us.x = f2bf(acc[0][gg] + bias);
        us.y = f2bf(acc[1][gg] + bias);
        us.z = f2bf(acc[2][gg] + bias);
        us.w = f2bf(acc[3][gg] + bias);
        const size_t idx = ((((size_t)t * 8 + grp) * 32 + w) * 512) +
                           gate * 128 + kl * 8 + b8l;
        *reinterpret_cast<ushort4*>(&xg[idx]) = us;
    }
}

#define GSTR 4096          // 8 b * 512 d floats per group (f32 fallback layout)
#define PSTR 32768         // per parity: 8 groups * GSTR (f32 fallback layout)
#define HQ4B 32768         // ull words per rotation buffer: 8 groups * 4096

// ---------------------------------------------------------------------------
// Kernel 2: persistent LSTM recurrence, split-bf16 MFMA + TAG-EMBEDDED
// 8B h exchange (merge sync into data, NO resets, NO flags, NO drains):
//  * each h element published as one 8B atomic store {packed(bf16hi|lo), tag}
//    with tag = t+1 (monotone). Consumer loads data words directly; a word
//    is stale iff tag != t -> re-poll only stale words. The stage IS the sync.
//  * 3 rotating buffers (768 KB, LLC-resident); monotone tags make old data
//    self-identifying -> no sentinel resets (R6's HBM-traffic pathology gone).
//  * lag safety: a wg publishing tag t has consumed all its step t-1 stage
//    loads, so buffers holding tag t-2 are dead before their next writer.
//  * zero-init = tag 0 everywhere = valid h_0 = 0 state for buffer 0 and
//    "stale" for buffers 1,2. Single memset.
//  * one __syncthreads per step; double-buffered LDS (2 x 16 KB).
// Unpack (v_perm), LDS swizzle, A-fragments, MFMA loop, combine: byte-
// identical to the R6-verified (refcheck-passed) path.
// ---------------------------------------------------------------------------
__global__ __launch_bounds__(256)
__attribute__((amdgpu_waves_per_eu(1, 1)))
void lstm_persist_mfma5(const ushort* __restrict__ Whh_hi,
                        const ushort* __restrict__ Whh_lo,
                        const ushort* __restrict__ xg,
                        unsigned long long* __restrict__ hq4, // [3][8][4096] {h,tag}
                        float* __restrict__ out)
{
    const int tid  = threadIdx.x;
    const int g    = blockIdx.x & 7;
    const int w    = blockIdx.x >> 3;
    const int k0   = w * 16;
    const int lane = tid & 63;
    const int wv   = tid >> 6;

    // per-lane output mapping
    const int  bcol   = lane & 15;              // batch col (valid < 8)
    const int  klane  = 4 * wv + (lane >> 4);   // k within wg's 16
    const bool active = bcol < 8;
    const int  b8     = lane & 7;

    const ushort* xg_wg = xg + (((size_t)g * 32 + w) * 512);

    // ---- A-fragments: W_hh split planes, held in regs for all 512 steps ----
    const int ar    = lane & 15;
    const int agate = ar & 3;
    const int ak    = k0 + 4 * wv + (ar >> 2);
    const size_t arow = ((size_t)agate * 512 + ak) * 512 + (size_t)(lane >> 4) * 8;
    bf16x8 afh[16], afl[16];
    #pragma unroll
    for (int ks = 0; ks < 16; ++ks) {
        afh[ks] = *reinterpret_cast<const bf16x8*>(Whh_hi + arow + ks * 32);
        afl[ks] = *reinterpret_cast<const bf16x8*>(Whh_lo + arow + ks * 32);
    }

    // LDS: 2 parities x { hi 8KB | lo 8KB }
    __shared__ __align__(16) char hsB[2 * 16384];

    float c_reg = 0.0f;

    float xv_cur[4] = {0.f, 0.f, 0.f, 0.f};
    if (active) {
        #pragma unroll
        for (int gate = 0; gate < 4; ++gate)
            xv_cur[gate] = bf2f(xg_wg[gate * 128 + klane * 8 + b8]);
    }

    unsigned int rot = 0;   // t % 3

    for (int t = 0; t < S; ++t) {
        const unsigned int wrot = (rot + 1 == 3) ? 0 : rot + 1;

        // ---- stage-with-tag-poll: 16 x 8B loads; re-poll stale words ----
        const unsigned long long* hsrc = hq4 + (size_t)rot * HQ4B + g * 4096;
        unsigned long long v0[8], v1[8];
        bool st0[8], st1[8];
        #pragma unroll
        for (int i = 0; i < 8; ++i) {
            const int e = 2 * (i * 256 + tid);   // even element index
            v0[i] = __hip_atomic_load(&hsrc[e],
                                      __ATOMIC_RELAXED, __HIP_MEMORY_SCOPE_AGENT);
            v1[i] = __hip_atomic_load(&hsrc[e + 1],
                                      __ATOMIC_RELAXED, __HIP_MEMORY_SCOPE_AGENT);
            st0[i] = ((unsigned int)(v0[i] >> 32) != (unsigned int)t);
            st1[i] = ((unsigned int)(v1[i] >> 32) != (unsigned int)t);
        }
        for (;;) {
            bool any = false;
            #pragma unroll
            for (int i = 0; i < 8; ++i) any |= st0[i] | st1[i];
            if (!__any(any)) break;
            __builtin_amdgcn_s_sleep(1);
            #pragma unroll
            for (int i = 0; i < 8; ++i) {
                const int e = 2 * (i * 256 + tid);
                if (st0[i]) {
                    v0[i] = __hip_atomic_load(&hsrc[e],
                                              __ATOMIC_RELAXED, __HIP_MEMORY_SCOPE_AGENT);
                    st0[i] = ((unsigned int)(v0[i] >> 32) != (unsigned int)t);
                }
                if (st1[i]) {
                    v1[i] = __hip_atomic_load(&hsrc[e + 1],
                                              __ATOMIC_RELAXED, __HIP_MEMORY_SCOPE_AGENT);
                    st1[i] = ((unsigned int)(v1[i] >> 32) != (unsigned int)t);
                }
            }
        }

        // ---- unpack (2 v_perm / pair) -> swizzled hi/lo LDS planes ----
        const int pbase = (t & 1) << 14;
        #pragma unroll
        for (int i = 0; i < 8; ++i) {
            const int e  = 2 * (i * 256 + tid);
            const int bb = e >> 9;
            const int dd = e & 511;          // even
            const unsigned int h0 = (unsigned int)v0[i];
            const unsigned int h1 = (unsigned int)v1[i];
            const unsigned int hiw = __builtin_amdgcn_perm(h1, h0, 0x07060302u);
            const unsigned int low = __builtin_amdgcn_perm(h1, h0, 0x05040100u);
            const int byteoff = ((((bb << 10) + (dd << 1)) ^ (bb << 4))) + pbase;
            *reinterpret_cast<unsigned int*>(hsB + byteoff) = hiw;
            *reinterpret_cast<unsigned int*>(hsB + 8192 + byteoff) = low;
        }
        __syncthreads();

        // ---- prefetch xg for t+1 (overlaps MFMA) ----
        float xv_nxt[4] = {0.f, 0.f, 0.f, 0.f};
        if (active && t + 1 < S) {
            const ushort* p = xg_wg + (size_t)(t + 1) * (8 * 32 * 512);
            #pragma unroll
            for (int gate = 0; gate < 4; ++gate)
                xv_nxt[gate] = bf2f(p[gate * 128 + klane * 8 + b8]);
        }

        // ---- MFMA: 16 K-steps x 3 products, 6 rotating accumulators ----
        f32x4 a0 = (f32x4){0.f,0.f,0.f,0.f}, a1 = a0, a2 = a0, a3 = a0, a4 = a0, a5 = a0;
        #pragma unroll
        for (int ks = 0; ks < 16; ++ks) {
            const int kbyte = ((((b8 << 10) + ((ks * 32 + (lane >> 4) * 8) << 1)) ^ (b8 << 4))) + pbase;
            const bf16x8 bh = *reinterpret_cast<const bf16x8*>(hsB + kbyte);
            const bf16x8 bl = *reinterpret_cast<const bf16x8*>(hsB + 8192 + kbyte);
            if (ks & 1) {
                a1 = __builtin_amdgcn_mfma_f32_16x16x32_bf16(afh[ks], bh, a1, 0, 0, 0);
                a3 = __builtin_amdgcn_mfma_f32_16x16x32_bf16(afl[ks], bh, a3, 0, 0, 0);
                a5 = __builtin_amdgcn_mfma_f32_16x16x32_bf16(afh[ks], bl, a5, 0, 0, 0);
            } else {
                a0 = __builtin_amdgcn_mfma_f32_16x16x32_bf16(afh[ks], bh, a0, 0, 0, 0);
                a2 = __builtin_amdgcn_mfma_f32_16x16x32_bf16(afl[ks], bh, a2, 0, 0, 0);
                a4 = __builtin_amdgcn_mfma_f32_16x16x32_bf16(afh[ks], bl, a4, 0, 0, 0);
            }
        }
        const f32x4 acc = (a0 + a1) + ((a2 + a3) + (a4 + a5));

        // ---- per-lane gate combine + h/c update + tagged publish ----
        float hn = 0.0f, cn = 0.0f;
        if (active) {
            const float ig = sigmoidf_(acc[0] + xv_cur[0]);
            const float fg = sigmoidf_(acc[1] + xv_cur[1]);
            const float gg = tanhf_(acc[2] + xv_cur[2]);
            const float og = sigmoidf_(acc[3] + xv_cur[3]);
            cn = fg * c_reg + ig * gg;
            c_reg = cn;
            hn = og * tanhf_(cn);

            ushort hh, hl;
            split_bf(hn, hh, hl);
            const unsigned long long pub =
                ((unsigned long long)(unsigned int)(t + 1) << 32) |
                (unsigned long long)(((unsigned int)hh << 16) | (unsigned int)hl);
            __hip_atomic_store(hq4 + (size_t)wrot * HQ4B + g * 4096 + b8 * 512 + k0 + klane,
                               pub, __ATOMIC_RELAXED, __HIP_MEMORY_SCOPE_AGENT);
        }

        // ---- out stores (off the exchange critical path) ----
        if (active) {
            out[((size_t)(g * 8 + b8) * S + t) * H + k0 + klane] = hn;
            if (t == S - 1) {
                const size_t OFF = (size_t)B * S * H;
                out[OFF + (size_t)(g * 8 + b8) * H + k0 + klane] = hn;
                out[OFF + (size_t)B * H + (size_t)(g * 8 + b8) * H + k0 + klane] = cn;
            }
        }

        xv_cur[0] = xv_nxt[0]; xv_cur[1] = xv_nxt[1];
        xv_cur[2] = xv_nxt[2]; xv_cur[3] = xv_nxt[3];
        rot = wrot;
    }
}

// ---------------------------------------------------------------------------
// Kernel 2 (old, fallback tier): vector-FMA persistent recurrence. Unchanged.
// ---------------------------------------------------------------------------
__global__ __launch_bounds__(256)
__attribute__((amdgpu_waves_per_eu(1, 1)))
void lstm_persist(const float* __restrict__ W_hh,
                  const ushort* __restrict__ xg,
                  float* __restrict__ hq,
                  unsigned int* __restrict__ bar,
                  float* __restrict__ out)
{
    const int tid = threadIdx.x;
    const int g   = blockIdx.x & 7;
    const int w   = blockIdx.x >> 3;
    const int k0  = w * 16;

    const int rp = tid & 31;
    const int d8 = tid >> 5;
    const int d0 = d8 * 64;

    const int b8 = tid >> 4;
    const int kl = tid & 15;

    unsigned int* bcnt = bar + g * 64;

    const ushort* xg_wg = xg + (((size_t)g * 32 + w) * 512);

    float4 wreg[2][16];
    #pragma unroll
    for (int r = 0; r < 2; ++r) {
        const int rl = 2 * rp + r;
        const int grow = (rl >> 4) * H + k0 + (rl & 15);
        const float4* wp = reinterpret_cast<const float4*>(W_hh + (size_t)grow * H + d0);
        #pragma unroll
        for (int i = 0; i < 16; ++i) wreg[r][i] = wp[i];
    }

    __shared__ float hs[8 * 512];
    __shared__ float part[8 * 8 * 64];

    float c_reg = 0.0f;

    float xv_cur[4] = {0.f, 0.f, 0.f, 0.f};
    if (tid < 128) {
        #pragma unroll
        for (int gate = 0; gate < 4; ++gate)
            xv_cur[gate] = bf2f(xg_wg[gate * 128 + kl * 8 + b8]);
    }

    for (int t = 0; t < S; ++t) {
        const unsigned long long* hsrc8 = reinterpret_cast<const unsigned long long*>(
            hq + (t & 1) * PSTR + g * GSTR);
        #pragma unroll
        for (int i = 0; i < 8; ++i) {
            const unsigned long long v = __hip_atomic_load(&hsrc8[i * 256 + tid],
                                                           __ATOMIC_RELAXED,
                                                           __HIP_MEMORY_SCOPE_AGENT);
            reinterpret_cast<unsigned long long*>(hs)[i * 256 + tid] = v;
        }
        __syncthreads();

        float xv_nxt[4] = {0.f, 0.f, 0.f, 0.f};
        if (tid < 128 && t + 1 < S) {
            const ushort* p = xg_wg + (size_t)(t + 1) * (8 * 32 * 512);
            #pragma unroll
            for (int gate = 0; gate < 4; ++gate)
                xv_nxt[gate] = bf2f(p[gate * 128 + kl * 8 + b8]);
        }

        float acc[2][8];
        #pragma unroll
        for (int r = 0; r < 2; ++r)
            #pragma unroll
            for (int b = 0; b < 8; ++b) acc[r][b] = 0.0f;

        #pragma unroll
        for (int b = 0; b < 8; ++b) {
            const float4* h4 = reinterpret_cast<const float4*>(hs + b * 512 + d0);
            #pragma unroll
            for (int i = 0; i < 16; ++i) {
                const float4 hv = h4[i];
                acc[0][b] += wreg[0][i].x * hv.x + wreg[0][i].y * hv.y +
                             wreg[0][i].z * hv.z + wreg[0][i].w * hv.w;
                acc[1][b] += wreg[1][i].x * hv.x + wreg[1][i].y * hv.y +
                             wreg[1][i].z * hv.z + wreg[1][i].w * hv.w;
            }
        }

        #pragma unroll
        for (int r = 0; r < 2; ++r)
            #pragma unroll
            for (int b = 0; b < 8; ++b)
                part[d8 * 512 + b * 64 + 2 * rp + r] = acc[r][b];
        __syncthreads();

        if (tid < 128) {
            float v[4];
            #pragma unroll
            for (int gate = 0; gate < 4; ++gate) {
                const int rl = gate * 16 + kl;
                float s = 0.0f;
                #pragma unroll
                for (int q = 0; q < 8; ++q) s += part[q * 512 + b8 * 64 + rl];
                v[gate] = s + xv_cur[gate];
            }
            const float ig = sigmoidf_(v[0]);
            const float fg = sigmoidf_(v[1]);
            const float gg = tanhf_(v[2]);
            const float og = sigmoidf_(v[3]);

            const float cn = fg * c_reg + ig * gg;
            c_reg = cn;
            const float hn = og * tanhf_(cn);

            __hip_atomic_store(&hq[((t & 1) ^ 1) * PSTR + g * GSTR + b8 * 512 + k0 + kl],
                               hn, __ATOMIC_RELAXED, __HIP_MEMORY_SCOPE_AGENT);
            out[((size_t)(g * 8 + b8) * S + t) * H + k0 + kl] = hn;
            if (t == S - 1) {
                const size_t OFF = (size_t)B * S * H;
                out[OFF + (size_t)(g * 8 + b8) * H + k0 + kl] = hn;
                out[OFF + (size_t)B * H + (size_t)(g * 8 + b8) * H + k0 + kl] = cn;
            }
        }

        __syncthreads();
        if (tid == 0) {
            __hip_atomic_fetch_add(bcnt, 1u, __ATOMIC_RELAXED,
                                   __HIP_MEMORY_SCOPE_AGENT);
            const unsigned int target = 32u * (unsigned int)(t + 1);
            while (__hip_atomic_load(bcnt, __ATOMIC_RELAXED,
                                     __HIP_MEMORY_SCOPE_AGENT) < target)
                __builtin_amdgcn_s_sleep(2);
        }
        __syncthreads();

        xv_cur[0] = xv_nxt[0]; xv_cur[1] = xv_nxt[1];
        xv_cur[2] = xv_nxt[2]; xv_cur[3] = xv_nxt[3];
    }
}

// ---------------------------------------------------------------------------
// Fallback (round-2 path) if ws_size is too small.
// ---------------------------------------------------------------------------
__global__ __launch_bounds__(128)
void lstm_step_fb(const int* __restrict__ tokens,
                  const float* __restrict__ emb,
                  const float* __restrict__ W_ih,
                  const float* __restrict__ W_hh,
                  const float* __restrict__ b_ih,
                  const float* __restrict__ b_hh,
                  const float* __restrict__ h_prev,
                  float* __restrict__ h_next,
                  float* __restrict__ c_st,
                  float* __restrict__ out,
                  int t)
{
    const int tid = threadIdx.x;
    const int b   = tid & 63;
    const int k   = blockIdx.x * 2 + (tid >> 6);
    const int token = tokens[b * S + t];
    const float* xrow = emb + (size_t)token * H;
    const float* hrow = h_prev + b * H;
    float acc[4];
    #pragma unroll
    for (int g = 0; g < 4; ++g) acc[g] = b_ih[g * H + k] + b_hh[g * H + k];
    for (int d = 0; d < H; ++d) {
        const float xv = xrow[d], hv = hrow[d];
        #pragma unroll
        for (int g = 0; g < 4; ++g)
            acc[g] += xv * W_ih[(size_t)(g * H + k) * H + d] + hv * W_hh[(size_t)(g * H + k) * H + d];
    }
    const float ig = sigmoidf_(acc[0]);
    const float fg = sigmoidf_(acc[1]);
    const float gg = tanhf(acc[2]);
    const float og = sigmoidf_(acc[3]);
    const int ck = b * H + k;
    const float cn = fg * c_st[ck] + ig * gg;
    c_st[ck] = cn;
    const float hn = og * tanhf(cn);
    h_next[ck] = hn;
    out[(size_t)b * S * H + (size_t)t * H + k] = hn;
    if (t == S - 1) {
        out[(size_t)B * S * H + ck] = hn;
        out[(size_t)B * S * H + B * H + ck] = cn;
    }
}

extern "C" void kernel_launch(void* const* d_in, const int* in_sizes, int n_in,
                              void* d_out, int out_size, void* d_ws, size_t ws_size,
                              hipStream_t stream)
{
    const int*   tokens = (const int*)d_in[0];
    const float* emb    = (const float*)d_in[1];
    const float* W_ih   = (const float*)d_in[2];
    const float* W_hh   = (const float*)d_in[3];
    const float* b_ih   = (const float*)d_in[4];
    const float* b_hh   = (const float*)d_in[5];
    float* out = (float*)d_out;

    const size_t XG_BYTES   = (size_t)S * G4 * B * 2;       // 134217728
    const size_t HQ4_BYTES  = (size_t)3 * HQ4B * 8;         // 786432 (3 tagged bufs)
    const size_t HQ_BYTES   = (size_t)2 * PSTR * 4;         // 262144 (legacy)
    const size_t FLAG_BYTES = 16384;                        // legacy bar area
    const size_t W_BYTES    = (size_t)G4 * H * 2;           // 2 MB per bf16 plane
    const size_t NEED_OLD   = XG_BYTES + HQ_BYTES + FLAG_BYTES;
    const size_t NEED_R1    = NEED_OLD + 2 * W_BYTES;       // + Wih hi/lo
    const size_t NEED_R4    = XG_BYTES + HQ4_BYTES + 4 * W_BYTES;

    if (ws_size >= NEED_R4) {
        ushort* xg = (ushort*)d_ws;
        unsigned long long* hq4 = (unsigned long long*)((char*)d_ws + XG_BYTES);
        ushort* Wih_hi = (ushort*)((char*)d_ws + XG_BYTES + HQ4_BYTES);
        ushort* Wih_lo = Wih_hi + (size_t)G4 * H;
        ushort* Whh_hi = Wih_lo + (size_t)G4 * H;
        ushort* Whh_lo = Whh_hi + (size_t)G4 * H;

        // zero = {h=0, tag=0}: valid h_0 state for buf0, stale for buf1/2.
        (void)hipMemsetAsync(hq4, 0x00, HQ4_BYTES, stream);

        w_split<<<dim3((G4 * H / 4) / 256), dim3(256), 0, stream>>>(W_ih, Wih_hi, Wih_lo);
        w_split<<<dim3((G4 * H / 4) / 256), dim3(256), 0, stream>>>(W_hh, Whh_hi, Whh_lo);

        xg_mfma<<<dim3(256, 16), dim3(256), 0, stream>>>(
            tokens, emb, Wih_hi, Wih_lo, b_ih, b_hh, xg);

        lstm_persist_mfma5<<<dim3(256), dim3(256), 0, stream>>>(
            Whh_hi, Whh_lo, xg, hq4, out);
    } else if (ws_size >= NEED_R1) {
        ushort* xg = (ushort*)d_ws;
        float*  hq = (float*)((char*)d_ws + XG_BYTES);
        unsigned int* bar = (unsigned int*)((char*)d_ws + XG_BYTES + HQ_BYTES);
        ushort* Wih_hi = (ushort*)((char*)d_ws + NEED_OLD);
        ushort* Wih_lo = Wih_hi + (size_t)G4 * H;

        (void)hipMemsetAsync(hq, 0, HQ_BYTES + FLAG_BYTES, stream);

        w_split<<<dim3((G4 * H / 4) / 256), dim3(256), 0, stream>>>(W_ih, Wih_hi, Wih_lo);

        xg_mfma<<<dim3(256, 16), dim3(256), 0, stream>>>(
            tokens, emb, Wih_hi, Wih_lo, b_ih, b_hh, xg);

        lstm_persist<<<dim3(256), dim3(256), 0, stream>>>(W_hh, xg, hq, bar, out);
    } else if (ws_size >= NEED_OLD) {
        ushort* xg = (ushort*)d_ws;
        float*  hq = (float*)((char*)d_ws + XG_BYTES);
        unsigned int* bar = (unsigned int*)((char*)d_ws + XG_BYTES + HQ_BYTES);

        (void)hipMemsetAsync(hq, 0, HQ_BYTES + FLAG_BYTES, stream);

        xg_gemm<<<dim3(S, 16), dim3(256), 0, stream>>>(tokens, emb, W_ih, b_ih, b_hh, xg);

        lstm_persist<<<dim3(256), dim3(256), 0, stream>>>(W_hh, xg, hq, bar, out);
    } else {
        float* c_st = (float*)d_ws;
        float* h0   = c_st + B * H;
        float* h1   = h0 + B * H;
        (void)hipMemsetAsync(d_ws, 0, (size_t)3 * B * H * sizeof(float), stream);
        for (int t = 0; t < S; ++t) {
            const float* hp = (t & 1) ? h1 : h0;
            float*       hn = (t & 1) ? h0 : h1;
            lstm_step_fb<<<dim3(256), dim3(128), 0, stream>>>(
                tokens, emb, W_ih, W_hh, b_ih, b_hh, hp, hn, c_st, out, t);
        }
    }
}

// Round 8
// 2453.528 us; speedup vs baseline: 1.3751x; 1.3547x over previous
//
#include <hip/hip_runtime.h>
#include <math.h>

#define B 64
#define S 512
#define H 512
#define G4 2048  // 4*H gate columns

typedef __attribute__((ext_vector_type(8))) short bf16x8;
typedef __attribute__((ext_vector_type(4))) float f32x4;

__device__ __forceinline__ float sigmoidf_(float x) {
    return 1.0f / (1.0f + __expf(-x));
}
__device__ __forceinline__ float tanhf_(float x) {
    return 2.0f / (1.0f + __expf(-2.0f * x)) - 1.0f;
}

// bf16 <-> f32 via raw bits (RNE)
__device__ __forceinline__ ushort f2bf(float f) {
    union { float f; unsigned int u; } v; v.f = f;
    unsigned int r = v.u + 0x7FFFu + ((v.u >> 16) & 1u);
    return (ushort)(r >> 16);
}
__device__ __forceinline__ float bf2f(ushort s) {
    union { unsigned int u; float f; } v; v.u = ((unsigned int)s) << 16;
    return v.f;
}
// split f32 into bf16 hi + bf16 lo, x ~= hi + lo to ~2^-18 rel
__device__ __forceinline__ void split_bf(float x, ushort& hi, ushort& lo) {
    const ushort h = f2bf(x);
    hi = h;
    lo = f2bf(x - bf2f(h));
}

// ---------------------------------------------------------------------------
// Pre-pass: split a f32 [2048][512] weight into bf16 hi/lo planes.
// grid.y selects which of two weight matrices (fused double-split launch).
// ---------------------------------------------------------------------------
__global__ __launch_bounds__(256)
void w_split2(const float* __restrict__ W0, ushort* __restrict__ W0hi, ushort* __restrict__ W0lo,
              const float* __restrict__ W1, ushort* __restrict__ W1hi, ushort* __restrict__ W1lo)
{
    const float* W = blockIdx.y ? W1 : W0;
    ushort* Whi = blockIdx.y ? W1hi : W0hi;
    ushort* Wlo = blockIdx.y ? W1lo : W0lo;
    const int i = blockIdx.x * 256 + threadIdx.x;  // float4 index, 262144 total
    const float4 v = reinterpret_cast<const float4*>(W)[i];
    ushort4 hi, lo;
    split_bf(v.x, hi.x, lo.x);
    split_bf(v.y, hi.y, lo.y);
    split_bf(v.z, hi.z, lo.z);
    split_bf(v.w, hi.w, lo.w);
    reinterpret_cast<ushort4*>(Whi)[i] = hi;
    reinterpret_cast<ushort4*>(Wlo)[i] = lo;
}

// ---------------------------------------------------------------------------
// Kernel 1 (fallback tier): xg = emb[tokens] @ W_ih^T + bias via MFMA.
// ---------------------------------------------------------------------------
__global__ __launch_bounds__(256)
void xg_mfma(const int* __restrict__ tokens,
             const float* __restrict__ emb,
             const ushort* __restrict__ Whi,
             const ushort* __restrict__ Wlo,
             const float* __restrict__ b_ih,
             const float* __restrict__ b_hh,
             ushort* __restrict__ xg)
{
    const int mtile = blockIdx.x;   // 0..255
    const int ntile = blockIdx.y;   // 0..15
    const int tid   = threadIdx.x;

    __shared__ ushort Ahi[128][32];
    __shared__ ushort Alo[128][32];
    __shared__ ushort Bhi[128][32];
    __shared__ ushort Blo[128][32];

    const int ar  = tid >> 3;   // 0..31
    const int seg = tid & 7;    // 0..7 -> 4-float col group
    const float* asrc[4];
    #pragma unroll
    for (int i = 0; i < 4; ++i) {
        const int m   = mtile * 128 + ar + i * 32;
        const int tok = tokens[(m & 63) * S + (m >> 6)];
        asrc[i] = emb + (size_t)tok * H + seg * 4;
    }

    const int br = tid >> 2;         // 0..63
    const int bc = (tid & 3) * 8;    // 8-ushort col group
    const ushort* bsrc_hi[2];
    const ushort* bsrc_lo[2];
    #pragma unroll
    for (int j = 0; j < 2; ++j) {
        const int n = ntile * 128 + br + j * 64;
        bsrc_hi[j] = Whi + (size_t)n * H + bc;
        bsrc_lo[j] = Wlo + (size_t)n * H + bc;
    }

    const int lane = tid & 63;
    const int wv   = tid >> 6;
    const int wr   = (wv >> 1) * 64;
    const int wc   = (wv & 1) * 64;
    const int fr   = lane & 15;
    const int ks   = lane >> 4;

    f32x4 acc[4][4];
    #pragma unroll
    for (int a = 0; a < 4; ++a)
        #pragma unroll
        for (int c = 0; c < 4; ++c)
            acc[a][c] = (f32x4){0.f, 0.f, 0.f, 0.f};

    for (int kc = 0; kc < 16; ++kc) {
        const int d0 = kc * 32;

        #pragma unroll
        for (int i = 0; i < 4; ++i) {
            const float4 v = *reinterpret_cast<const float4*>(asrc[i] + d0);
            ushort4 hi, lo;
            split_bf(v.x, hi.x, lo.x);
            split_bf(v.y, hi.y, lo.y);
            split_bf(v.z, hi.z, lo.z);
            split_bf(v.w, hi.w, lo.w);
            const int r = ar + i * 32;
            *reinterpret_cast<ushort4*>(&Ahi[r][seg * 4]) = hi;
            *reinterpret_cast<ushort4*>(&Alo[r][seg * 4]) = lo;
        }
        #pragma unroll
        for (int j = 0; j < 2; ++j) {
            const int r = br + j * 64;
            *reinterpret_cast<uint4*>(&Bhi[r][bc]) =
                *reinterpret_cast<const uint4*>(bsrc_hi[j] + d0);
            *reinterpret_cast<uint4*>(&Blo[r][bc]) =
                *reinterpret_cast<const uint4*>(bsrc_lo[j] + d0);
        }
        __syncthreads();

        bf16x8 ah[4], al[4];
        #pragma unroll
        for (int fm = 0; fm < 4; ++fm) {
            ah[fm] = *reinterpret_cast<const bf16x8*>(&Ahi[wr + fm * 16 + fr][ks * 8]);
            al[fm] = *reinterpret_cast<const bf16x8*>(&Alo[wr + fm * 16 + fr][ks * 8]);
        }
        #pragma unroll
        for (int fn = 0; fn < 4; ++fn) {
            const bf16x8 bh = *reinterpret_cast<const bf16x8*>(&Bhi[wc + fn * 16 + fr][ks * 8]);
            const bf16x8 bl = *reinterpret_cast<const bf16x8*>(&Blo[wc + fn * 16 + fr][ks * 8]);
            #pragma unroll
            for (int fm = 0; fm < 4; ++fm) {
                acc[fm][fn] = __builtin_amdgcn_mfma_f32_16x16x32_bf16(ah[fm], bh, acc[fm][fn], 0, 0, 0);
                acc[fm][fn] = __builtin_amdgcn_mfma_f32_16x16x32_bf16(al[fm], bh, acc[fm][fn], 0, 0, 0);
                acc[fm][fn] = __builtin_amdgcn_mfma_f32_16x16x32_bf16(ah[fm], bl, acc[fm][fn], 0, 0, 0);
            }
        }
        __syncthreads();
    }

    #pragma unroll
    for (int fn = 0; fn < 4; ++fn) {
        const int col  = ntile * 128 + wc + fn * 16 + fr;
        const float bias = b_ih[col] + b_hh[col];
        const int gate = col >> 9;
        const int k    = col & 511;
        const int w    = k >> 4;
        const int kl   = k & 15;
        #pragma unroll
        for (int fm = 0; fm < 4; ++fm) {
            const int row = mtile * 128 + wr + fm * 16 + ks * 4;
            const int t   = row >> 6;
            const int b   = row & 63;
            const int g   = b >> 3;
            const int b8  = b & 7;
            ushort4 us;
            us.x = f2bf(acc[fm][fn][0] + bias);
            us.y = f2bf(acc[fm][fn][1] + bias);
            us.z = f2bf(acc[fm][fn][2] + bias);
            us.w = f2bf(acc[fm][fn][3] + bias);
            const size_t idx = ((((size_t)t * 8 + g) * 32 + w) * 512) +
                               gate * 128 + kl * 8 + b8;
            *reinterpret_cast<ushort4*>(&xg[idx]) = us;
        }
    }
}

#define GSTR 4096          // 8 b * 512 d floats per group
#define PSTR 32768         // per parity: 8 groups * GSTR

// ---------------------------------------------------------------------------
// Kernel 2 (new): FUSED persistent LSTM. Recurrence body, h exchange (f32),
// and RMW barrier are byte-identical to the verified R2 kernel (1686us,
// absmax 0.0078). Added: in-kernel xg computation filling the barrier-wait
// idle window:
//  * Wih hi/lo A-fragments in VGPRs (same 64 gate-rows as the Whh slice).
//  * emb rows for the wg's 8 batches staged (split-bf16, same swizzle) into
//    a double-buffered LDS pair ONE STEP AHEAD (tokens known upfront; emb
//    loads are issued during the h-MFMA phase, LDS-written before the
//    arrival barrier, consumed after the release barrier).
//  * xg-phase: 48 MFMAs on emb LDS -> f32x4 xga; xv = xga + bias. Runs at
//    the top of each step, BEFORE the h stage - pure idle-window fill.
// No xg array, no xg_mfma dispatch, no per-step xg HBM reads.
// ---------------------------------------------------------------------------
__global__ __launch_bounds__(256)
__attribute__((amdgpu_waves_per_eu(1, 1)))
void lstm_persist_fused(const ushort* __restrict__ Whh_hi,
                        const ushort* __restrict__ Whh_lo,
                        const ushort* __restrict__ Wih_hi,
                        const ushort* __restrict__ Wih_lo,
                        const int*    __restrict__ tokens,
                        const float*  __restrict__ emb,
                        const float*  __restrict__ b_ih,
                        const float*  __restrict__ b_hh,
                        float* __restrict__ hq,          // [2][8][8][512] f32
                        unsigned int* __restrict__ bar,  // 8 counters, 256B apart
                        float* __restrict__ out)
{
    const int tid  = threadIdx.x;
    const int g    = blockIdx.x & 7;
    const int w    = blockIdx.x >> 3;
    const int k0   = w * 16;
    const int lane = tid & 63;
    const int wv   = tid >> 6;

    const int  bcol   = lane & 15;
    const int  klane  = 4 * wv + (lane >> 4);
    const bool active = bcol < 8;
    const int  b8     = lane & 7;

    unsigned int* bcnt = bar + g * 64;

    // ---- A-fragments: W_hh AND W_ih split planes in VGPRs (256 regs) ----
    const int ar    = lane & 15;
    const int agate = ar & 3;
    const int ak    = k0 + 4 * wv + (ar >> 2);
    const size_t arow = ((size_t)agate * 512 + ak) * 512 + (size_t)(lane >> 4) * 8;
    bf16x8 afh[16], afl[16], wfh[16], wfl[16];
    #pragma unroll
    for (int ks = 0; ks < 16; ++ks) {
        afh[ks] = *reinterpret_cast<const bf16x8*>(Whh_hi + arow + ks * 32);
        afl[ks] = *reinterpret_cast<const bf16x8*>(Whh_lo + arow + ks * 32);
        wfh[ks] = *reinterpret_cast<const bf16x8*>(Wih_hi + arow + ks * 32);
        wfl[ks] = *reinterpret_cast<const bf16x8*>(Wih_lo + arow + ks * 32);
    }

    // ---- per-lane bias for its 4 gates at k = k0+klane ----
    float bias[4] = {0.f, 0.f, 0.f, 0.f};
    if (active) {
        #pragma unroll
        for (int j = 0; j < 4; ++j) {
            const int col = j * 512 + k0 + klane;
            bias[j] = b_ih[col] + b_hh[col];
        }
    }

    __shared__ ushort hs_hi[8 * 512];       // 8 KiB, XOR-swizzled [b][d]
    __shared__ ushort hs_lo[8 * 512];       // 8 KiB
    __shared__ ushort em_hi[2][8 * 512];    // 16 KiB (dbuf)
    __shared__ ushort em_lo[2][8 * 512];    // 16 KiB

    char* hs_hi_c = reinterpret_cast<char*>(hs_hi);
    char* hs_lo_c = reinterpret_cast<char*>(hs_lo);
    char* em_hi_c = reinterpret_cast<char*>(em_hi);
    char* em_lo_c = reinterpret_cast<char*>(em_lo);

    float c_reg = 0.0f;

    // ---- prologue: stage emb(t=0) into parity 0 ----
    {
        #pragma unroll
        for (int i = 0; i < 8; ++i) {
            const int tok = tokens[(g * 8 + i) * S + 0];
            const float2 v = *reinterpret_cast<const float2*>(
                emb + (size_t)tok * H + 2 * tid);
            ushort h0, l0, h1, l1;
            split_bf(v.x, h0, l0);
            split_bf(v.y, h1, l1);
            const int byteoff = ((i << 10) + (tid << 2)) ^ (i << 4);
            *reinterpret_cast<unsigned int*>(em_hi_c + byteoff) =
                ((unsigned int)h1 << 16) | (unsigned int)h0;
            *reinterpret_cast<unsigned int*>(em_lo_c + byteoff) =
                ((unsigned int)l1 << 16) | (unsigned int)l0;
        }
    }
    __syncthreads();

    for (int t = 0; t < S; ++t) {
        const int ep = (t & 1) * 8192;   // emb parity byte base

        // ---- xg-phase: 48 MFMAs on emb LDS (independent of h; fills the
        //      window while other wgs finish publishing h_t) ----
        f32x4 x0 = (f32x4){0.f,0.f,0.f,0.f}, x1 = x0, x2 = x0, x3 = x0, x4 = x0, x5 = x0;
        #pragma unroll
        for (int ks = 0; ks < 16; ++ks) {
            const int kbyte = (((b8 << 10) + ((ks * 32 + (lane >> 4) * 8) << 1)) ^ (b8 << 4)) + ep;
            const bf16x8 bh = *reinterpret_cast<const bf16x8*>(em_hi_c + kbyte);
            const bf16x8 bl = *reinterpret_cast<const bf16x8*>(em_lo_c + kbyte);
            if (ks & 1) {
                x1 = __builtin_amdgcn_mfma_f32_16x16x32_bf16(wfh[ks], bh, x1, 0, 0, 0);
                x3 = __builtin_amdgcn_mfma_f32_16x16x32_bf16(wfl[ks], bh, x3, 0, 0, 0);
                x5 = __builtin_amdgcn_mfma_f32_16x16x32_bf16(wfh[ks], bl, x5, 0, 0, 0);
            } else {
                x0 = __builtin_amdgcn_mfma_f32_16x16x32_bf16(wfh[ks], bh, x0, 0, 0, 0);
                x2 = __builtin_amdgcn_mfma_f32_16x16x32_bf16(wfl[ks], bh, x2, 0, 0, 0);
                x4 = __builtin_amdgcn_mfma_f32_16x16x32_bf16(wfh[ks], bl, x4, 0, 0, 0);
            }
        }
        const f32x4 xga = (x0 + x1) + ((x2 + x3) + (x4 + x5));
        float xv[4];
        #pragma unroll
        for (int j = 0; j < 4; ++j) xv[j] = xga[j] + bias[j];

        // ---- stage h_t: 16 floats/thread -> split -> LDS (R2-identical) ----
        const unsigned long long* hsrc8 = reinterpret_cast<const unsigned long long*>(
            hq + (t & 1) * PSTR + g * GSTR);
        unsigned long long hv[8];
        #pragma unroll
        for (int i = 0; i < 8; ++i)
            hv[i] = __hip_atomic_load(&hsrc8[i * 256 + tid],
                                      __ATOMIC_RELAXED, __HIP_MEMORY_SCOPE_AGENT);
        #pragma unroll
        for (int i = 0; i < 8; ++i) {
            const int e  = 2 * (i * 256 + tid);
            const int bb = e >> 9;
            const int dd = e & 511;          // even
            union { unsigned long long u; float f[2]; } uv; uv.u = hv[i];
            ushort h0, l0, h1, l1;
            split_bf(uv.f[0], h0, l0);
            split_bf(uv.f[1], h1, l1);
            const int byteoff = ((bb << 10) + (dd << 1)) ^ (bb << 4);
            *reinterpret_cast<unsigned int*>(hs_hi_c + byteoff) =
                ((unsigned int)h1 << 16) | (unsigned int)h0;
            *reinterpret_cast<unsigned int*>(hs_lo_c + byteoff) =
                ((unsigned int)l1 << 16) | (unsigned int)l0;
        }

        // ---- issue emb(t+1) loads (independent; hide under sync+MFMA) ----
        float2 ev[8];
        if (t + 1 < S) {
            #pragma unroll
            for (int i = 0; i < 8; ++i) {
                const int tok = tokens[(g * 8 + i) * S + (t + 1)];
                ev[i] = *reinterpret_cast<const float2*>(
                    emb + (size_t)tok * H + 2 * tid);
            }
        }
        __syncthreads();

        // ---- h-MFMA: 16 K-steps x 3 products, 6 rotating accumulators ----
        f32x4 a0 = (f32x4){0.f,0.f,0.f,0.f}, a1 = a0, a2 = a0, a3 = a0, a4 = a0, a5 = a0;
        #pragma unroll
        for (int ks = 0; ks < 16; ++ks) {
            const int kbyte = ((b8 << 10) + ((ks * 32 + (lane >> 4) * 8) << 1)) ^ (b8 << 4);
            const bf16x8 bh = *reinterpret_cast<const bf16x8*>(hs_hi_c + kbyte);
            const bf16x8 bl = *reinterpret_cast<const bf16x8*>(hs_lo_c + kbyte);
            if (ks & 1) {
                a1 = __builtin_amdgcn_mfma_f32_16x16x32_bf16(afh[ks], bh, a1, 0, 0, 0);
                a3 = __builtin_amdgcn_mfma_f32_16x16x32_bf16(afl[ks], bh, a3, 0, 0, 0);
                a5 = __builtin_amdgcn_mfma_f32_16x16x32_bf16(afh[ks], bl, a5, 0, 0, 0);
            } else {
                a0 = __builtin_amdgcn_mfma_f32_16x16x32_bf16(afh[ks], bh, a0, 0, 0, 0);
                a2 = __builtin_amdgcn_mfma_f32_16x16x32_bf16(afl[ks], bh, a2, 0, 0, 0);
                a4 = __builtin_amdgcn_mfma_f32_16x16x32_bf16(afh[ks], bl, a4, 0, 0, 0);
            }
        }
        const f32x4 acc = (a0 + a1) + ((a2 + a3) + (a4 + a5));

        // ---- per-lane gate combine + h/c update (R2-identical) ----
        float hn = 0.0f, cn = 0.0f;
        if (active) {
            const float ig = sigmoidf_(acc[0] + xv[0]);
            const float fg = sigmoidf_(acc[1] + xv[1]);
            const float gg = tanhf_(acc[2] + xv[2]);
            const float og = sigmoidf_(acc[3] + xv[3]);
            cn = fg * c_reg + ig * gg;
            c_reg = cn;
            hn = og * tanhf_(cn);
            __hip_atomic_store(&hq[((t & 1) ^ 1) * PSTR + g * GSTR + b8 * 512 + k0 + klane],
                               hn, __ATOMIC_RELAXED, __HIP_MEMORY_SCOPE_AGENT);
            out[((size_t)(g * 8 + b8) * S + t) * H + k0 + klane] = hn;
            if (t == S - 1) {
                const size_t OFF = (size_t)B * S * H;
                out[OFF + (size_t)(g * 8 + b8) * H + k0 + klane] = hn;
                out[OFF + (size_t)B * H + (size_t)(g * 8 + b8) * H + k0 + klane] = cn;
            }
        }

        // ---- split emb(t+1) regs -> LDS parity (t+1)&1 (fenced by the
        //      release barrier before next step's xg-phase reads it) ----
        if (t + 1 < S) {
            const int epn = ((t + 1) & 1) * 8192;
            #pragma unroll
            for (int i = 0; i < 8; ++i) {
                ushort h0, l0, h1, l1;
                split_bf(ev[i].x, h0, l0);
                split_bf(ev[i].y, h1, l1);
                const int byteoff = (((i << 10) + (tid << 2)) ^ (i << 4)) + epn;
                *reinterpret_cast<unsigned int*>(em_hi_c + byteoff) =
                    ((unsigned int)h1 << 16) | (unsigned int)h0;
                *reinterpret_cast<unsigned int*>(em_lo_c + byteoff) =
                    ((unsigned int)l1 << 16) | (unsigned int)l0;
            }
        }

        // ---- group barrier (R2-identical: RMW counter + 2 syncs) ----
        __syncthreads();     // drains each wave's vmcnt -> h stores visible
        if (tid == 0) {
            __hip_atomic_fetch_add(bcnt, 1u, __ATOMIC_RELAXED,
                                   __HIP_MEMORY_SCOPE_AGENT);
            const unsigned int target = 32u * (unsigned int)(t + 1);
            while (__hip_atomic_load(bcnt, __ATOMIC_RELAXED,
                                     __HIP_MEMORY_SCOPE_AGENT) < target)
                __builtin_amdgcn_s_sleep(2);
        }
        __syncthreads();
    }
}

// ---------------------------------------------------------------------------
// Kernel 2 (fallback tier): R2-verified persist (consumes xg array).
// ---------------------------------------------------------------------------
__global__ __launch_bounds__(256)
__attribute__((amdgpu_waves_per_eu(1, 1)))
void lstm_persist_mfma(const ushort* __restrict__ Whh_hi,
                       const ushort* __restrict__ Whh_lo,
                       const ushort* __restrict__ xg,
                       float* __restrict__ hq,
                       unsigned int* __restrict__ bar,
                       float* __restrict__ out)
{
    const int tid  = threadIdx.x;
    const int g    = blockIdx.x & 7;
    const int w    = blockIdx.x >> 3;
    const int k0   = w * 16;
    const int lane = tid & 63;
    const int wv   = tid >> 6;

    const int  bcol   = lane & 15;
    const int  klane  = 4 * wv + (lane >> 4);
    const bool active = bcol < 8;
    const int  b8     = lane & 7;

    unsigned int* bcnt = bar + g * 64;
    const ushort* xg_wg = xg + (((size_t)g * 32 + w) * 512);

    const int ar    = lane & 15;
    const int agate = ar & 3;
    const int ak    = k0 + 4 * wv + (ar >> 2);
    const size_t arow = ((size_t)agate * 512 + ak) * 512 + (size_t)(lane >> 4) * 8;
    bf16x8 afh[16], afl[16];
    #pragma unroll
    for (int ks = 0; ks < 16; ++ks) {
        afh[ks] = *reinterpret_cast<const bf16x8*>(Whh_hi + arow + ks * 32);
        afl[ks] = *reinterpret_cast<const bf16x8*>(Whh_lo + arow + ks * 32);
    }

    __shared__ ushort hs_hi[8 * 512];
    __shared__ ushort hs_lo[8 * 512];

    float c_reg = 0.0f;

    float xv_cur[4] = {0.f, 0.f, 0.f, 0.f};
    if (active) {
        #pragma unroll
        for (int gate = 0; gate < 4; ++gate)
            xv_cur[gate] = bf2f(xg_wg[gate * 128 + klane * 8 + b8]);
    }

    char* hs_hi_c = reinterpret_cast<char*>(hs_hi);
    char* hs_lo_c = reinterpret_cast<char*>(hs_lo);

    for (int t = 0; t < S; ++t) {
        const unsigned long long* hsrc8 = reinterpret_cast<const unsigned long long*>(
            hq + (t & 1) * PSTR + g * GSTR);
        unsigned long long hv[8];
        #pragma unroll
        for (int i = 0; i < 8; ++i)
            hv[i] = __hip_atomic_load(&hsrc8[i * 256 + tid],
                                      __ATOMIC_RELAXED, __HIP_MEMORY_SCOPE_AGENT);
        #pragma unroll
        for (int i = 0; i < 8; ++i) {
            const int e  = 2 * (i * 256 + tid);
            const int bb = e >> 9;
            const int dd = e & 511;
            union { unsigned long long u; float f[2]; } uv; uv.u = hv[i];
            ushort h0, l0, h1, l1;
            split_bf(uv.f[0], h0, l0);
            split_bf(uv.f[1], h1, l1);
            const int byteoff = ((bb << 10) + (dd << 1)) ^ (bb << 4);
            *reinterpret_cast<unsigned int*>(hs_hi_c + byteoff) =
                ((unsigned int)h1 << 16) | (unsigned int)h0;
            *reinterpret_cast<unsigned int*>(hs_lo_c + byteoff) =
                ((unsigned int)l1 << 16) | (unsigned int)l0;
        }
        __syncthreads();

        float xv_nxt[4] = {0.f, 0.f, 0.f, 0.f};
        if (active && t + 1 < S) {
            const ushort* p = xg_wg + (size_t)(t + 1) * (8 * 32 * 512);
            #pragma unroll
            for (int gate = 0; gate < 4; ++gate)
                xv_nxt[gate] = bf2f(p[gate * 128 + klane * 8 + b8]);
        }

        f32x4 a0 = (f32x4){0.f,0.f,0.f,0.f}, a1 = a0, a2 = a0, a3 = a0, a4 = a0, a5 = a0;
        #pragma unroll
        for (int ks = 0; ks < 16; ++ks) {
            const int kbyte = ((b8 << 10) + ((ks * 32 + (lane >> 4) * 8) << 1)) ^ (b8 << 4);
            const bf16x8 bh = *reinterpret_cast<const bf16x8*>(hs_hi_c + kbyte);
            const bf16x8 bl = *reinterpret_cast<const bf16x8*>(hs_lo_c + kbyte);
            if (ks & 1) {
                a1 = __builtin_amdgcn_mfma_f32_16x16x32_bf16(afh[ks], bh, a1, 0, 0, 0);
                a3 = __builtin_amdgcn_mfma_f32_16x16x32_bf16(afl[ks], bh, a3, 0, 0, 0);
                a5 = __builtin_amdgcn_mfma_f32_16x16x32_bf16(afh[ks], bl, a5, 0, 0, 0);
            } else {
                a0 = __builtin_amdgcn_mfma_f32_16x16x32_bf16(afh[ks], bh, a0, 0, 0, 0);
                a2 = __builtin_amdgcn_mfma_f32_16x16x32_bf16(afl[ks], bh, a2, 0, 0, 0);
                a4 = __builtin_amdgcn_mfma_f32_16x16x32_bf16(afh[ks], bl, a4, 0, 0, 0);
            }
        }
        const f32x4 acc = (a0 + a1) + ((a2 + a3) + (a4 + a5));

        float hn = 0.0f, cn = 0.0f;
        if (active) {
            const float ig = sigmoidf_(acc[0] + xv_cur[0]);
            const float fg = sigmoidf_(acc[1] + xv_cur[1]);
            const float gg = tanhf_(acc[2] + xv_cur[2]);
            const float og = sigmoidf_(acc[3] + xv_cur[3]);
            cn = fg * c_reg + ig * gg;
            c_reg = cn;
            hn = og * tanhf_(cn);
            __hip_atomic_store(&hq[((t & 1) ^ 1) * PSTR + g * GSTR + b8 * 512 + k0 + klane],
                               hn, __ATOMIC_RELAXED, __HIP_MEMORY_SCOPE_AGENT);
            out[((size_t)(g * 8 + b8) * S + t) * H + k0 + klane] = hn;
            if (t == S - 1) {
                const size_t OFF = (size_t)B * S * H;
                out[OFF + (size_t)(g * 8 + b8) * H + k0 + klane] = hn;
                out[OFF + (size_t)B * H + (size_t)(g * 8 + b8) * H + k0 + klane] = cn;
            }
        }

        __syncthreads();
        if (tid == 0) {
            __hip_atomic_fetch_add(bcnt, 1u, __ATOMIC_RELAXED,
                                   __HIP_MEMORY_SCOPE_AGENT);
            const unsigned int target = 32u * (unsigned int)(t + 1);
            while (__hip_atomic_load(bcnt, __ATOMIC_RELAXED,
                                     __HIP_MEMORY_SCOPE_AGENT) < target)
                __builtin_amdgcn_s_sleep(2);
        }
        __syncthreads();

        xv_cur[0] = xv_nxt[0]; xv_cur[1] = xv_nxt[1];
        xv_cur[2] = xv_nxt[2]; xv_cur[3] = xv_nxt[3];
    }
}

// ---------------------------------------------------------------------------
// Last-resort fallback.
// ---------------------------------------------------------------------------
__global__ __launch_bounds__(128)
void lstm_step_fb(const int* __restrict__ tokens,
                  const float* __restrict__ emb,
                  const float* __restrict__ W_ih,
                  const float* __restrict__ W_hh,
                  const float* __restrict__ b_ih,
                  const float* __restrict__ b_hh,
                  const float* __restrict__ h_prev,
                  float* __restrict__ h_next,
                  float* __restrict__ c_st,
                  float* __restrict__ out,
                  int t)
{
    const int tid = threadIdx.x;
    const int b   = tid & 63;
    const int k   = blockIdx.x * 2 + (tid >> 6);
    const int token = tokens[b * S + t];
    const float* xrow = emb + (size_t)token * H;
    const float* hrow = h_prev + b * H;
    float acc[4];
    #pragma unroll
    for (int g = 0; g < 4; ++g) acc[g] = b_ih[g * H + k] + b_hh[g * H + k];
    for (int d = 0; d < H; ++d) {
        const float xv = xrow[d], hv = hrow[d];
        #pragma unroll
        for (int g = 0; g < 4; ++g)
            acc[g] += xv * W_ih[(size_t)(g * H + k) * H + d] + hv * W_hh[(size_t)(g * H + k) * H + d];
    }
    const float ig = sigmoidf_(acc[0]);
    const float fg = sigmoidf_(acc[1]);
    const float gg = tanhf(acc[2]);
    const float og = sigmoidf_(acc[3]);
    const int ck = b * H + k;
    const float cn = fg * c_st[ck] + ig * gg;
    c_st[ck] = cn;
    const float hn = og * tanhf(cn);
    h_next[ck] = hn;
    out[(size_t)b * S * H + (size_t)t * H + k] = hn;
    if (t == S - 1) {
        out[(size_t)B * S * H + ck] = hn;
        out[(size_t)B * S * H + B * H + ck] = cn;
    }
}

extern "C" void kernel_launch(void* const* d_in, const int* in_sizes, int n_in,
                              void* d_out, int out_size, void* d_ws, size_t ws_size,
                              hipStream_t stream)
{
    const int*   tokens = (const int*)d_in[0];
    const float* emb    = (const float*)d_in[1];
    const float* W_ih   = (const float*)d_in[2];
    const float* W_hh   = (const float*)d_in[3];
    const float* b_ih   = (const float*)d_in[4];
    const float* b_hh   = (const float*)d_in[5];
    float* out = (float*)d_out;

    const size_t HQ_BYTES   = (size_t)2 * PSTR * 4;         // 262144
    const size_t BAR_BYTES  = 8 * 64 * 4;                   // 2048
    const size_t W_BYTES    = (size_t)G4 * H * 2;           // 2 MB per bf16 plane
    const size_t XG_BYTES   = (size_t)S * G4 * B * 2;       // 134 MB (fallback only)
    const size_t NEED_FUSED = HQ_BYTES + BAR_BYTES + 4 * W_BYTES;   // ~8.25 MB
    const size_t NEED_R2    = XG_BYTES + HQ_BYTES + BAR_BYTES + 4 * W_BYTES;

    if (ws_size >= NEED_FUSED && ws_size < NEED_R2) {
        // small-ws fused tier (shouldn't normally trigger; same as below)
    }

    if (ws_size >= NEED_FUSED) {
        float* hq = (float*)d_ws;
        unsigned int* bar = (unsigned int*)((char*)d_ws + HQ_BYTES);
        ushort* Wih_hi = (ushort*)((char*)d_ws + HQ_BYTES + BAR_BYTES);
        ushort* Wih_lo = Wih_hi + (size_t)G4 * H;
        ushort* Whh_hi = Wih_lo + (size_t)G4 * H;
        ushort* Whh_lo = Whh_hi + (size_t)G4 * H;

        (void)hipMemsetAsync(hq, 0, HQ_BYTES + BAR_BYTES, stream);

        w_split2<<<dim3((G4 * H / 4) / 256, 2), dim3(256), 0, stream>>>(
            W_ih, Wih_hi, Wih_lo, W_hh, Whh_hi, Whh_lo);

        lstm_persist_fused<<<dim3(256), dim3(256), 0, stream>>>(
            Whh_hi, Whh_lo, Wih_hi, Wih_lo, tokens, emb, b_ih, b_hh,
            hq, bar, out);
    } else {
        float* c_st = (float*)d_ws;
        float* h0   = c_st + B * H;
        float* h1   = h0 + B * H;
        (void)hipMemsetAsync(d_ws, 0, (size_t)3 * B * H * sizeof(float), stream);
        for (int t = 0; t < S; ++t) {
            const float* hp = (t & 1) ? h1 : h0;
            float*       hn = (t & 1) ? h0 : h1;
            lstm_step_fb<<<dim3(256), dim3(128), 0, stream>>>(
                tokens, emb, W_ih, W_hh, b_ih, b_hh, hp, hn, c_st, out, t);
        }
    }
}

// Round 10
// 1933.302 us; speedup vs baseline: 1.7452x; 1.2691x over previous
//
#include <hip/hip_runtime.h>
#include <math.h>

#define B 64
#define S 512
#define H 512
#define G4 2048  // 4*H gate columns

typedef __attribute__((ext_vector_type(8))) short bf16x8;
typedef __attribute__((ext_vector_type(4))) float f32x4;

__device__ __forceinline__ float sigmoidf_(float x) {
    return 1.0f / (1.0f + __expf(-x));
}
__device__ __forceinline__ float tanhf_(float x) {
    return 2.0f / (1.0f + __expf(-2.0f * x)) - 1.0f;
}

// bf16 <-> f32 via raw bits (RNE)
__device__ __forceinline__ ushort f2bf(float f) {
    union { float f; unsigned int u; } v; v.f = f;
    unsigned int r = v.u + 0x7FFFu + ((v.u >> 16) & 1u);
    return (ushort)(r >> 16);
}
__device__ __forceinline__ float bf2f(ushort s) {
    union { unsigned int u; float f; } v; v.u = ((unsigned int)s) << 16;
    return v.f;
}
// split f32 into bf16 hi + bf16 lo, x ~= hi + lo to ~2^-18 rel
__device__ __forceinline__ void split_bf(float x, ushort& hi, ushort& lo) {
    const ushort h = f2bf(x);
    hi = h;
    lo = f2bf(x - bf2f(h));
}

// ---------------------------------------------------------------------------
// Pre-pass: split f32 [2048][512] weights into bf16 hi/lo planes.
// grid.y selects which of two weight matrices (verified in R8 run).
// ---------------------------------------------------------------------------
__global__ __launch_bounds__(256)
void w_split2(const float* __restrict__ W0, ushort* __restrict__ W0hi, ushort* __restrict__ W0lo,
              const float* __restrict__ W1, ushort* __restrict__ W1hi, ushort* __restrict__ W1lo)
{
    const float* W = blockIdx.y ? W1 : W0;
    ushort* Whi = blockIdx.y ? W1hi : W0hi;
    ushort* Wlo = blockIdx.y ? W1lo : W0lo;
    const int i = blockIdx.x * 256 + threadIdx.x;  // float4 index, 262144 total
    const float4 v = reinterpret_cast<const float4*>(W)[i];
    ushort4 hi, lo;
    split_bf(v.x, hi.x, lo.x);
    split_bf(v.y, hi.y, lo.y);
    split_bf(v.z, hi.z, lo.z);
    split_bf(v.w, hi.w, lo.w);
    reinterpret_cast<ushort4*>(Whi)[i] = hi;
    reinterpret_cast<ushort4*>(Wlo)[i] = lo;
}

// ---------------------------------------------------------------------------
// Kernel 1: xg = emb[tokens] @ W_ih^T + bias via split-bf16 MFMA.
// (verified: R1/R2 runs, absmax 0.0078)
// ---------------------------------------------------------------------------
__global__ __launch_bounds__(256)
void xg_mfma(const int* __restrict__ tokens,
             const float* __restrict__ emb,
             const ushort* __restrict__ Whi,
             const ushort* __restrict__ Wlo,
             const float* __restrict__ b_ih,
             const float* __restrict__ b_hh,
             ushort* __restrict__ xg)
{
    const int mtile = blockIdx.x;   // 0..255
    const int ntile = blockIdx.y;   // 0..15
    const int tid   = threadIdx.x;

    __shared__ ushort Ahi[128][32];
    __shared__ ushort Alo[128][32];
    __shared__ ushort Bhi[128][32];
    __shared__ ushort Blo[128][32];

    const int ar  = tid >> 3;   // 0..31
    const int seg = tid & 7;    // 0..7 -> 4-float col group
    const float* asrc[4];
    #pragma unroll
    for (int i = 0; i < 4; ++i) {
        const int m   = mtile * 128 + ar + i * 32;
        const int tok = tokens[(m & 63) * S + (m >> 6)];
        asrc[i] = emb + (size_t)tok * H + seg * 4;
    }

    const int br = tid >> 2;         // 0..63
    const int bc = (tid & 3) * 8;    // 8-ushort col group
    const ushort* bsrc_hi[2];
    const ushort* bsrc_lo[2];
    #pragma unroll
    for (int j = 0; j < 2; ++j) {
        const int n = ntile * 128 + br + j * 64;
        bsrc_hi[j] = Whi + (size_t)n * H + bc;
        bsrc_lo[j] = Wlo + (size_t)n * H + bc;
    }

    const int lane = tid & 63;
    const int wv   = tid >> 6;
    const int wr   = (wv >> 1) * 64;
    const int wc   = (wv & 1) * 64;
    const int fr   = lane & 15;
    const int ks   = lane >> 4;

    f32x4 acc[4][4];
    #pragma unroll
    for (int a = 0; a < 4; ++a)
        #pragma unroll
        for (int c = 0; c < 4; ++c)
            acc[a][c] = (f32x4){0.f, 0.f, 0.f, 0.f};

    for (int kc = 0; kc < 16; ++kc) {
        const int d0 = kc * 32;

        #pragma unroll
        for (int i = 0; i < 4; ++i) {
            const float4 v = *reinterpret_cast<const float4*>(asrc[i] + d0);
            ushort4 hi, lo;
            split_bf(v.x, hi.x, lo.x);
            split_bf(v.y, hi.y, lo.y);
            split_bf(v.z, hi.z, lo.z);
            split_bf(v.w, hi.w, lo.w);
            const int r = ar + i * 32;
            *reinterpret_cast<ushort4*>(&Ahi[r][seg * 4]) = hi;
            *reinterpret_cast<ushort4*>(&Alo[r][seg * 4]) = lo;
        }
        #pragma unroll
        for (int j = 0; j < 2; ++j) {
            const int r = br + j * 64;
            *reinterpret_cast<uint4*>(&Bhi[r][bc]) =
                *reinterpret_cast<const uint4*>(bsrc_hi[j] + d0);
            *reinterpret_cast<uint4*>(&Blo[r][bc]) =
                *reinterpret_cast<const uint4*>(bsrc_lo[j] + d0);
        }
        __syncthreads();

        bf16x8 ah[4], al[4];
        #pragma unroll
        for (int fm = 0; fm < 4; ++fm) {
            ah[fm] = *reinterpret_cast<const bf16x8*>(&Ahi[wr + fm * 16 + fr][ks * 8]);
            al[fm] = *reinterpret_cast<const bf16x8*>(&Alo[wr + fm * 16 + fr][ks * 8]);
        }
        #pragma unroll
        for (int fn = 0; fn < 4; ++fn) {
            const bf16x8 bh = *reinterpret_cast<const bf16x8*>(&Bhi[wc + fn * 16 + fr][ks * 8]);
            const bf16x8 bl = *reinterpret_cast<const bf16x8*>(&Blo[wc + fn * 16 + fr][ks * 8]);
            #pragma unroll
            for (int fm = 0; fm < 4; ++fm) {
                acc[fm][fn] = __builtin_amdgcn_mfma_f32_16x16x32_bf16(ah[fm], bh, acc[fm][fn], 0, 0, 0);
                acc[fm][fn] = __builtin_amdgcn_mfma_f32_16x16x32_bf16(al[fm], bh, acc[fm][fn], 0, 0, 0);
                acc[fm][fn] = __builtin_amdgcn_mfma_f32_16x16x32_bf16(ah[fm], bl, acc[fm][fn], 0, 0, 0);
            }
        }
        __syncthreads();
    }

    #pragma unroll
    for (int fn = 0; fn < 4; ++fn) {
        const int col  = ntile * 128 + wc + fn * 16 + fr;
        const float bias = b_ih[col] + b_hh[col];
        const int gate = col >> 9;
        const int k    = col & 511;
        const int w    = k >> 4;
        const int kl   = k & 15;
        #pragma unroll
        for (int fm = 0; fm < 4; ++fm) {
            const int row = mtile * 128 + wr + fm * 16 + ks * 4;
            const int t   = row >> 6;
            const int b   = row & 63;
            const int g   = b >> 3;
            const int b8  = b & 7;
            ushort4 us;
            us.x = f2bf(acc[fm][fn][0] + bias);
            us.y = f2bf(acc[fm][fn][1] + bias);
            us.z = f2bf(acc[fm][fn][2] + bias);
            us.w = f2bf(acc[fm][fn][3] + bias);
            const size_t idx = ((((size_t)t * 8 + g) * 32 + w) * 512) +
                               gate * 128 + kl * 8 + b8;
            *reinterpret_cast<ushort4*>(&xg[idx]) = us;
        }
    }
}

#define GSTR 4096          // 8 b * 512 d floats per group
#define PSTR 32768         // per parity: 8 groups * GSTR

// ---------------------------------------------------------------------------
// Kernel 2: persistent LSTM recurrence via split-bf16 MFMA.
// R2-EXACT (verified: 1686 us/dispatch, absmax 0.0078).
// Per wg (256 thr, 4 waves): 64 gate rows (16 k x 4 gates) x 8 batches.
// W_hh hi/lo A-fragments live in VGPRs for the whole kernel (128 VGPRs).
// C/D layout (verified): col = lane&15, row = (lane>>4)*4 + reg
//   => each lane's 4 acc regs are the 4 gates of one (k, b).
// h staged in LDS as bf16 hi/lo with XOR swizzle (b&7)<<4 on byte addr.
// Exchange: f32 4B agent-scope atomics through LLC (the only mechanism of
// 6 tried that is both correct and fastest; see R3-R9 ledger).
// ---------------------------------------------------------------------------
__global__ __launch_bounds__(256)
__attribute__((amdgpu_waves_per_eu(1, 1)))
void lstm_persist_mfma(const ushort* __restrict__ Whh_hi,
                       const ushort* __restrict__ Whh_lo,
                       const ushort* __restrict__ xg,
                       float* __restrict__ hq,         // [2][8][8][512]
                       unsigned int* __restrict__ bar, // 8 counters, 64-uint stride
                       float* __restrict__ out)
{
    const int tid  = threadIdx.x;
    const int g    = blockIdx.x & 7;
    const int w    = blockIdx.x >> 3;
    const int k0   = w * 16;
    const int lane = tid & 63;
    const int wv   = tid >> 6;

    unsigned int* bcnt = bar + g * 64;   // 256 B apart per group

    // per-lane output mapping
    const int  bcol   = lane & 15;              // batch col (valid < 8)
    const int  klane  = 4 * wv + (lane >> 4);   // k within wg's 16
    const bool active = bcol < 8;
    const int  b8     = lane & 7;

    const ushort* xg_wg = xg + (((size_t)g * 32 + w) * 512);

    // ---- A-fragments: W_hh split planes, held in regs for all 512 steps ----
    // A row r = lane&15 -> gate = r&3, k = k0 + 4*wv + (r>>2)
    const int ar    = lane & 15;
    const int agate = ar & 3;
    const int ak    = k0 + 4 * wv + (ar >> 2);
    const size_t arow = ((size_t)agate * 512 + ak) * 512 + (size_t)(lane >> 4) * 8;
    bf16x8 afh[16], afl[16];
    #pragma unroll
    for (int ks = 0; ks < 16; ++ks) {
        afh[ks] = *reinterpret_cast<const bf16x8*>(Whh_hi + arow + ks * 32);
        afl[ks] = *reinterpret_cast<const bf16x8*>(Whh_lo + arow + ks * 32);
    }

    __shared__ ushort hs_hi[8 * 512];   // 8 KiB, XOR-swizzled [b][d]
    __shared__ ushort hs_lo[8 * 512];   // 8 KiB

    float c_reg = 0.0f;

    float xv_cur[4] = {0.f, 0.f, 0.f, 0.f};
    if (active) {
        #pragma unroll
        for (int gate = 0; gate < 4; ++gate)
            xv_cur[gate] = bf2f(xg_wg[gate * 128 + klane * 8 + b8]);
    }

    char* hs_hi_c = reinterpret_cast<char*>(hs_hi);
    char* hs_lo_c = reinterpret_cast<char*>(hs_lo);

    for (int t = 0; t < S; ++t) {
        // ---- stage h_prev: 16 floats/thread -> split -> LDS (swizzled) ----
        const unsigned long long* hsrc8 = reinterpret_cast<const unsigned long long*>(
            hq + (t & 1) * PSTR + g * GSTR);
        unsigned long long hv[8];
        #pragma unroll
        for (int i = 0; i < 8; ++i)
            hv[i] = __hip_atomic_load(&hsrc8[i * 256 + tid],
                                      __ATOMIC_RELAXED, __HIP_MEMORY_SCOPE_AGENT);
        #pragma unroll
        for (int i = 0; i < 8; ++i) {
            const int e  = 2 * (i * 256 + tid);
            const int bb = e >> 9;
            const int dd = e & 511;          // even
            union { unsigned long long u; float f[2]; } uv; uv.u = hv[i];
            ushort h0, l0, h1, l1;
            split_bf(uv.f[0], h0, l0);
            split_bf(uv.f[1], h1, l1);
            const int byteoff = ((bb << 10) + (dd << 1)) ^ (bb << 4);
            *reinterpret_cast<unsigned int*>(hs_hi_c + byteoff) =
                ((unsigned int)h1 << 16) | (unsigned int)h0;
            *reinterpret_cast<unsigned int*>(hs_lo_c + byteoff) =
                ((unsigned int)l1 << 16) | (unsigned int)l0;
        }
        __syncthreads();

        // ---- prefetch xg for t+1 (overlaps MFMA) ----
        float xv_nxt[4] = {0.f, 0.f, 0.f, 0.f};
        if (active && t + 1 < S) {
            const ushort* p = xg_wg + (size_t)(t + 1) * (8 * 32 * 512);
            #pragma unroll
            for (int gate = 0; gate < 4; ++gate)
                xv_nxt[gate] = bf2f(p[gate * 128 + klane * 8 + b8]);
        }

        // ---- MFMA: 16 K-steps x 3 products, 6 rotating accumulators ----
        f32x4 a0 = (f32x4){0.f,0.f,0.f,0.f}, a1 = a0, a2 = a0, a3 = a0, a4 = a0, a5 = a0;
        #pragma unroll
        for (int ks = 0; ks < 16; ++ks) {
            const int kbyte = ((b8 << 10) + ((ks * 32 + (lane >> 4) * 8) << 1)) ^ (b8 << 4);
            const bf16x8 bh = *reinterpret_cast<const bf16x8*>(hs_hi_c + kbyte);
            const bf16x8 bl = *reinterpret_cast<const bf16x8*>(hs_lo_c + kbyte);
            if (ks & 1) {
                a1 = __builtin_amdgcn_mfma_f32_16x16x32_bf16(afh[ks], bh, a1, 0, 0, 0);
                a3 = __builtin_amdgcn_mfma_f32_16x16x32_bf16(afl[ks], bh, a3, 0, 0, 0);
                a5 = __builtin_amdgcn_mfma_f32_16x16x32_bf16(afh[ks], bl, a5, 0, 0, 0);
            } else {
                a0 = __builtin_amdgcn_mfma_f32_16x16x32_bf16(afh[ks], bh, a0, 0, 0, 0);
                a2 = __builtin_amdgcn_mfma_f32_16x16x32_bf16(afl[ks], bh, a2, 0, 0, 0);
                a4 = __builtin_amdgcn_mfma_f32_16x16x32_bf16(afh[ks], bl, a4, 0, 0, 0);
            }
        }
        const f32x4 acc = (a0 + a1) + ((a2 + a3) + (a4 + a5));

        // ---- per-lane gate combine + h/c update ----
        float hn = 0.0f, cn = 0.0f;
        if (active) {
            const float ig = sigmoidf_(acc[0] + xv_cur[0]);
            const float fg = sigmoidf_(acc[1] + xv_cur[1]);
            const float gg = tanhf_(acc[2] + xv_cur[2]);
            const float og = sigmoidf_(acc[3] + xv_cur[3]);
            cn = fg * c_reg + ig * gg;
            c_reg = cn;
            hn = og * tanhf_(cn);
            __hip_atomic_store(&hq[((t & 1) ^ 1) * PSTR + g * GSTR + b8 * 512 + k0 + klane],
                               hn, __ATOMIC_RELAXED, __HIP_MEMORY_SCOPE_AGENT);
            out[((size_t)(g * 8 + b8) * S + t) * H + k0 + klane] = hn;
            if (t == S - 1) {
                const size_t OFF = (size_t)B * S * H;
                out[OFF + (size_t)(g * 8 + b8) * H + k0 + klane] = hn;
                out[OFF + (size_t)B * H + (size_t)(g * 8 + b8) * H + k0 + klane] = cn;
            }
        }

        // ---- group barrier (R2-exact: 2 syncthreads + tid0 RMW + poll) ----
        __syncthreads();     // drains each wave's vmcnt -> h stores visible
        if (tid == 0) {
            __hip_atomic_fetch_add(bcnt, 1u, __ATOMIC_RELAXED,
                                   __HIP_MEMORY_SCOPE_AGENT);
            const unsigned int target = 32u * (unsigned int)(t + 1);
            while (__hip_atomic_load(bcnt, __ATOMIC_RELAXED,
                                     __HIP_MEMORY_SCOPE_AGENT) < target)
                __builtin_amdgcn_s_sleep(2);
        }
        __syncthreads();

        xv_cur[0] = xv_nxt[0]; xv_cur[1] = xv_nxt[1];
        xv_cur[2] = xv_nxt[2]; xv_cur[3] = xv_nxt[3];
    }
}

// ---------------------------------------------------------------------------
// Last-resort fallback (small workspace).
// ---------------------------------------------------------------------------
__global__ __launch_bounds__(128)
void lstm_step_fb(const int* __restrict__ tokens,
                  const float* __restrict__ emb,
                  const float* __restrict__ W_ih,
                  const float* __restrict__ W_hh,
                  const float* __restrict__ b_ih,
                  const float* __restrict__ b_hh,
                  const float* __restrict__ h_prev,
                  float* __restrict__ h_next,
                  float* __restrict__ c_st,
                  float* __restrict__ out,
                  int t)
{
    const int tid = threadIdx.x;
    const int b   = tid & 63;
    const int k   = blockIdx.x * 2 + (tid >> 6);
    const int token = tokens[b * S + t];
    const float* xrow = emb + (size_t)token * H;
    const float* hrow = h_prev + b * H;
    float acc[4];
    #pragma unroll
    for (int g = 0; g < 4; ++g) acc[g] = b_ih[g * H + k] + b_hh[g * H + k];
    for (int d = 0; d < H; ++d) {
        const float xv = xrow[d], hv = hrow[d];
        #pragma unroll
        for (int g = 0; g < 4; ++g)
            acc[g] += xv * W_ih[(size_t)(g * H + k) * H + d] + hv * W_hh[(size_t)(g * H + k) * H + d];
    }
    const float ig = sigmoidf_(acc[0]);
    const float fg = sigmoidf_(acc[1]);
    const float gg = tanhf(acc[2]);
    const float og = sigmoidf_(acc[3]);
    const int ck = b * H + k;
    const float cn = fg * c_st[ck] + ig * gg;
    c_st[ck] = cn;
    const float hn = og * tanhf(cn);
    h_next[ck] = hn;
    out[(size_t)b * S * H + (size_t)t * H + k] = hn;
    if (t == S - 1) {
        out[(size_t)B * S * H + ck] = hn;
        out[(size_t)B * S * H + B * H + ck] = cn;
    }
}

extern "C" void kernel_launch(void* const* d_in, const int* in_sizes, int n_in,
                              void* d_out, int out_size, void* d_ws, size_t ws_size,
                              hipStream_t stream)
{
    const int*   tokens = (const int*)d_in[0];
    const float* emb    = (const float*)d_in[1];
    const float* W_ih   = (const float*)d_in[2];
    const float* W_hh   = (const float*)d_in[3];
    const float* b_ih   = (const float*)d_in[4];
    const float* b_hh   = (const float*)d_in[5];
    float* out = (float*)d_out;

    const size_t XG_BYTES  = (size_t)S * G4 * B * 2;       // 134217728
    const size_t HQ_BYTES  = (size_t)2 * PSTR * 4;         // 262144
    const size_t BAR_BYTES = 8 * 64 * 4;                   // 2048
    const size_t W_BYTES   = (size_t)G4 * H * 2;           // 2 MB per bf16 plane
    const size_t NEED = XG_BYTES + HQ_BYTES + BAR_BYTES + 4 * W_BYTES;

    if (ws_size >= NEED) {
        ushort* xg = (ushort*)d_ws;
        float*  hq = (float*)((char*)d_ws + XG_BYTES);
        unsigned int* bar = (unsigned int*)((char*)d_ws + XG_BYTES + HQ_BYTES);
        ushort* Wih_hi = (ushort*)((char*)d_ws + XG_BYTES + HQ_BYTES + BAR_BYTES);
        ushort* Wih_lo = Wih_hi + (size_t)G4 * H;
        ushort* Whh_hi = Wih_lo + (size_t)G4 * H;
        ushort* Whh_lo = Whh_hi + (size_t)G4 * H;

        (void)hipMemsetAsync(hq, 0, HQ_BYTES + BAR_BYTES, stream);

        w_split2<<<dim3((G4 * H / 4) / 256, 2), dim3(256), 0, stream>>>(
            W_ih, Wih_hi, Wih_lo, W_hh, Whh_hi, Whh_lo);

        xg_mfma<<<dim3(256, 16), dim3(256), 0, stream>>>(
            tokens, emb, Wih_hi, Wih_lo, b_ih, b_hh, xg);

        lstm_persist_mfma<<<dim3(256), dim3(256), 0, stream>>>(
            Whh_hi, Whh_lo, xg, hq, bar, out);
    } else {
        float* c_st = (float*)d_ws;
        float* h0   = c_st + B * H;
        float* h1   = h0 + B * H;
        (void)hipMemsetAsync(d_ws, 0, (size_t)3 * B * H * sizeof(float), stream);
        for (int t = 0; t < S; ++t) {
            const float* hp = (t & 1) ? h1 : h0;
            float*       hn = (t & 1) ? h0 : h1;
            lstm_step_fb<<<dim3(256), dim3(128), 0, stream>>>(
                tokens, emb, W_ih, W_hh, b_ih, b_hh, hp, hn, c_st, out, t);
        }
    }
}